// Round 6
// baseline (735.461 us; speedup 1.0000x reference)
//
#include <hip/hip_runtime.h>
#include <math.h>

#define B_    64
#define N_    1024
#define D_    128
#define DP1   129
#define NC_   10
#define QB    128     // queries per block (4 waves x 32)
#define KT    32      // key tile
#define SCf   0.31622776601683794f
#define SCALE 0.08804509063256238f   // 1/sqrt(129)

typedef __bf16 bf16x8 __attribute__((ext_vector_type(8)));
typedef float  f32x16 __attribute__((ext_vector_type(16)));

#define MFMA(a, b, c) __builtin_amdgcn_mfma_f32_32x32x16_bf16((a), (b), (c), 0, 0, 0)

static __device__ __forceinline__ float dpp_add_step(float f, int ctrl, int rmask) {
    if (ctrl == 0x111) { int t = __builtin_amdgcn_update_dpp(0, __builtin_bit_cast(int, f), 0x111, 0xf, 0xf, true); return f + __builtin_bit_cast(float, t); }
    if (ctrl == 0x112) { int t = __builtin_amdgcn_update_dpp(0, __builtin_bit_cast(int, f), 0x112, 0xf, 0xf, true); return f + __builtin_bit_cast(float, t); }
    if (ctrl == 0x114) { int t = __builtin_amdgcn_update_dpp(0, __builtin_bit_cast(int, f), 0x114, 0xf, 0xf, true); return f + __builtin_bit_cast(float, t); }
    if (ctrl == 0x118) { int t = __builtin_amdgcn_update_dpp(0, __builtin_bit_cast(int, f), 0x118, 0xf, 0xf, true); return f + __builtin_bit_cast(float, t); }
    if (ctrl == 0x142 && rmask == 0xa) { int t = __builtin_amdgcn_update_dpp(0, __builtin_bit_cast(int, f), 0x142, 0xa, 0xf, true); return f + __builtin_bit_cast(float, t); }
    { int t = __builtin_amdgcn_update_dpp(0, __builtin_bit_cast(int, f), 0x143, 0xc, 0xf, true); return f + __builtin_bit_cast(float, t); }
}

// full 64-lane sum, result broadcast to all lanes
static __device__ __forceinline__ float wave_sum64(float f) {
    f = dpp_add_step(f, 0x111, 0xf);
    f = dpp_add_step(f, 0x112, 0xf);
    f = dpp_add_step(f, 0x114, 0xf);
    f = dpp_add_step(f, 0x118, 0xf);
    f = dpp_add_step(f, 0x142, 0xa);
    f = dpp_add_step(f, 0x143, 0xc);
    return __builtin_bit_cast(float, __builtin_amdgcn_readlane(__builtin_bit_cast(int, f), 63));
}

// per-32-lane-half sum, each lane gets its half's total
static __device__ __forceinline__ float half_sum32(float f, int half) {
    f = dpp_add_step(f, 0x111, 0xf);
    f = dpp_add_step(f, 0x112, 0xf);
    f = dpp_add_step(f, 0x114, 0xf);
    f = dpp_add_step(f, 0x118, 0xf);
    f = dpp_add_step(f, 0x142, 0xa);
    float s0 = __builtin_bit_cast(float, __builtin_amdgcn_readlane(__builtin_bit_cast(int, f), 31));
    float s1 = __builtin_bit_cast(float, __builtin_amdgcn_readlane(__builtin_bit_cast(int, f), 63));
    return half ? s1 : s0;
}

static __device__ __forceinline__ float readlane_f(float v, int lane) {
    return __builtin_bit_cast(float, __builtin_amdgcn_readlane(__builtin_bit_cast(int, v), lane));
}

static __device__ __forceinline__ bf16x8 ld_lds8(const __bf16* p) {
    union { bf16x8 v; unsigned long long q[2]; } u;
    u.q[0] = *(const unsigned long long*)(p);
    u.q[1] = *(const unsigned long long*)(p + 4);
    return u.v;
}

// ---------------- mask dtype detection (int32 vs packed int8 bool) ----------------
__global__ __launch_bounds__(256) void k_detect_mask(const int* __restrict__ mask_w,
                                                     int* __restrict__ flag) {
    __shared__ int bad;
    if (threadIdx.x == 0) bad = 0;
    __syncthreads();
    int local = 0;
    for (int i = threadIdx.x; i < 16384; i += 256) {
        int v = mask_w[i];
        if (v != 0 && v != 1) local = 1;
    }
    if (local) atomicOr(&bad, 1);
    __syncthreads();
    if (threadIdx.x == 0) *flag = bad;   // 1 => data is packed int8 bools
}

static __device__ __forceinline__ int read_mask(const int* mw, int is_i8, int idx) {
    if (is_i8) return (int)((const unsigned char*)mw)[idx];
    return mw[idx];
}

// ---------------- Wo -> bf16 hi/lo, layout [o][144] (K padded 129->144 with zeros) ----------------
__global__ __launch_bounds__(256) void k_prep_wo(const float* __restrict__ Wo,
                                                 __bf16* __restrict__ Woh,
                                                 __bf16* __restrict__ Wol) {
    int idx = blockIdx.x * 256 + threadIdx.x;
    if (idx >= 128 * 144) return;
    int o = idx / 144, d = idx - o * 144;
    float v = (d < DP1) ? Wo[o * DP1 + d] : 0.f;
    __bf16 h = (__bf16)v;
    Woh[idx] = h;
    Wol[idx] = (__bf16)(v - (float)h);
}

// ---------------- embedding + Lorentz expmap0 -> bf16 hi/lo rows + comp0/comp128 f32 ----------------
__global__ __launch_bounds__(256) void k_prep(const int* __restrict__ tok,
                                              const float* __restrict__ emb,
                                              __bf16* __restrict__ Xh, __bf16* __restrict__ Xl,
                                              float* __restrict__ X0g, float* __restrict__ X128g) {
    __shared__ float Xf[64][132];
    const int t = threadIdx.x, w = t >> 6, l = t & 63;
    const int base = blockIdx.x * 64;
    for (int it = 0; it < 16; ++it) {
        const int tk = w * 16 + it;
        const int id = tok[base + tk];
        const float2 v = ((const float2*)(emb + (size_t)id * D_))[l];
        float s = wave_sum64(v.x * v.x + v.y * v.y);
        float nv = fmaxf(sqrtf(s), 1e-7f);
        float a = SCf * nv;
        float a2 = a * a;
        float shc, ch;
        if (a < 0.5f) {
            shc = 1.f + a2 * (1.f/6.f) * (1.f + a2 * (1.f/20.f) * (1.f + a2 * (1.f/42.f)));
            ch  = 1.f + a2 * 0.5f * (1.f + a2 * (1.f/12.f) * (1.f + a2 * (1.f/30.f)));
        } else {
            float ea = __expf(a), ei = 1.f / ea;
            ch = 0.5f * (ea + ei);
            shc = 0.5f * (ea - ei) / a;
        }
        Xf[tk][1 + 2 * l] = v.x * shc;
        Xf[tk][2 + 2 * l] = v.y * shc;
        if (l == 0) Xf[tk][0] = ch / SCf;
    }
    __syncthreads();
    const int tk2 = t >> 2, dg = (t & 3) * 32;
    for (int i = 0; i < 32; i += 8) {
        bf16x8 hv, lv;
        #pragma unroll
        for (int j = 0; j < 8; ++j) {
            float f = Xf[tk2][dg + i + j];
            __bf16 h = (__bf16)f;
            hv[j] = h;
            lv[j] = (__bf16)(f - (float)h);
        }
        *(bf16x8*)(Xh + (size_t)(base + tk2) * D_ + dg + i) = hv;
        *(bf16x8*)(Xl + (size_t)(base + tk2) * D_ + dg + i) = lv;
    }
    if (t < 64) {
        X0g[base + t]   = Xf[t][0];
        X128g[base + t] = Xf[t][D_];
    }
}

// ---------------- fused MFMA attention: scores + exp + centroid + renorm + projection + expmap ----------------
__global__ __launch_bounds__(256, 2) void k_attn(
        const __bf16* __restrict__ Xh, const __bf16* __restrict__ Xl,
        const float* __restrict__ X0g, const float* __restrict__ X128g,
        const int* __restrict__ mask, const int* __restrict__ mflag,
        const __bf16* __restrict__ Woh, const __bf16* __restrict__ Wol,
        const float* __restrict__ bo,
        float* __restrict__ Y, float* __restrict__ Y2) {
    extern __shared__ char smem[];
    __bf16* Krow = (__bf16*)smem;                   // 16896 B
    __bf16* XTb  = (__bf16*)(smem + 16896);         // 18432 B
    __bf16* Pb   = (__bf16*)(smem + 35328);         // 18432 B
    __shared__ float K0s[KT];
    __shared__ float K128s[KT];
    __shared__ int   Ms[KT];

    const int b    = blockIdx.y;
    const int qb   = blockIdx.x * QB;
    const int t    = threadIdx.x;
    const int w    = t >> 6;
    const int l    = t & 63;
    const int l31  = l & 31;
    const int half = l >> 5;
    const int is8  = *mflag;

    const size_t qrow = (size_t)(b * N_ + qb + w * 32 + l31);
    bf16x8 qfh[8], qfl[8];
    #pragma unroll
    for (int ks = 0; ks < 8; ++ks) {
        qfh[ks] = *(const bf16x8*)(Xh + qrow * D_ + ks * 16 + half * 8);
        qfl[ks] = *(const bf16x8*)(Xl + qrow * D_ + ks * 16 + half * 8);
    }
    float q0[16], q128[16];
    #pragma unroll
    for (int r = 0; r < 16; ++r) {
        const int qr = (r & 3) + 8 * (r >> 2) + 4 * half;
        q0[r]   = X0g[b * N_ + qb + w * 32 + qr];
        q128[r] = X128g[b * N_ + qb + w * 32 + qr];
    }

    f32x16 accM[4] = {};
    float  mu128p[16] = {};

    for (int kt = 0; kt < N_ / KT; ++kt) {
        __syncthreads();
        {
            const int key = t >> 3, ck = t & 7;
            const size_t krow = (size_t)(b * N_ + kt * KT + key);
            #pragma unroll
            for (int ch = 0; ch < 2; ++ch) {
                const int c0 = ck * 8 + 64 * ch;
                bf16x8 vh = *(const bf16x8*)(Xh + krow * D_ + c0);
                bf16x8 vl = *(const bf16x8*)(Xl + krow * D_ + c0);
                union { bf16x8 v; unsigned long long q[2]; } uh, ul;
                uh.v = vh; ul.v = vl;
                *(unsigned long long*)(Krow + key * 132 + c0)            = uh.q[0];
                *(unsigned long long*)(Krow + key * 132 + c0 + 4)        = uh.q[1];
                *(unsigned long long*)(Krow + 4224 + key * 132 + c0)     = ul.q[0];
                *(unsigned long long*)(Krow + 4224 + key * 132 + c0 + 4) = ul.q[1];
                #pragma unroll
                for (int j = 0; j < 8; ++j) {
                    XTb[(c0 + j) * 36 + key]        = vh[j];
                    XTb[4608 + (c0 + j) * 36 + key] = vl[j];
                }
            }
            if (t < KT) {
                K0s[t]   = X0g[b * N_ + kt * KT + t];
                K128s[t] = X128g[b * N_ + kt * KT + t];
                Ms[t]    = read_mask(mask, is8, b * N_ + kt * KT + t);
            }
        }
        __syncthreads();

        f32x16 accS = {};
        #pragma unroll
        for (int ks = 0; ks < 8; ++ks) {
            bf16x8 bh = ld_lds8(Krow + l31 * 132 + ks * 16 + half * 8);
            bf16x8 bl = ld_lds8(Krow + 4224 + l31 * 132 + ks * 16 + half * 8);
            accS = MFMA(qfh[ks], bh, accS);
            accS = MFMA(qfh[ks], bl, accS);
            accS = MFMA(qfl[ks], bh, accS);
        }
        const float k0v = K0s[l31], k128v = K128s[l31];
        const int   mv  = Ms[l31];
        #pragma unroll
        for (int r = 0; r < 16; ++r) {
            float sc = (2.f * q0[r] * k0v - accS[r] - q128[r] * k128v) * SCALE;
            float e  = mv ? __expf(sc) : 0.f;
            mu128p[r] += e * k128v;
            __bf16 eh = (__bf16)e;
            __bf16 el = (__bf16)(e - (float)eh);
            const int qr = (r & 3) + 8 * (r >> 2) + 4 * half;
            Pb[(w * 2 + 0) * 1152 + qr * 36 + l31] = eh;
            Pb[(w * 2 + 1) * 1152 + qr * 36 + l31] = el;
        }

        #pragma unroll
        for (int ks = 0; ks < 2; ++ks) {
            bf16x8 ah = ld_lds8(Pb + (w * 2 + 0) * 1152 + l31 * 36 + ks * 16 + half * 8);
            bf16x8 al = ld_lds8(Pb + (w * 2 + 1) * 1152 + l31 * 36 + ks * 16 + half * 8);
            #pragma unroll
            for (int nt = 0; nt < 4; ++nt) {
                bf16x8 bh = ld_lds8(XTb + (nt * 32 + l31) * 36 + ks * 16 + half * 8);
                bf16x8 bl = ld_lds8(XTb + 4608 + (nt * 32 + l31) * 36 + ks * 16 + half * 8);
                accM[nt] = MFMA(ah, bh, accM[nt]);
                accM[nt] = MFMA(ah, bl, accM[nt]);
                accM[nt] = MFMA(al, bh, accM[nt]);
            }
        }
    }

    #pragma unroll
    for (int r = 0; r < 16; ++r) mu128p[r] = half_sum32(mu128p[r], half);
    float rno[16];
    #pragma unroll
    for (int r = 0; r < 16; ++r) {
        float p = 0.f;
        #pragma unroll
        for (int nt = 0; nt < 4; ++nt) p += accM[nt][r] * accM[nt][r];
        if (l31 == 0) p -= 2.f * accM[0][r] * accM[0][r];
        p = half_sum32(p, half);
        float negI = -(p + mu128p[r] * mu128p[r]);
        negI = fmaxf(negI, 1e-7f);
        rno[r] = 1.f / (SCf * sqrtf(negI));
    }
    #pragma unroll
    for (int nt = 0; nt < 4; ++nt)
        #pragma unroll
        for (int r = 0; r < 16; ++r) accM[nt][r] *= rno[r];
    #pragma unroll
    for (int r = 0; r < 16; ++r) mu128p[r] *= rno[r];

    __syncthreads();
    __bf16* MuA = (__bf16*)smem + w * (32 * 148);
    #pragma unroll
    for (int r = 0; r < 16; ++r) {
        const int qr = (r & 3) + 8 * (r >> 2) + 4 * half;
        #pragma unroll
        for (int nt = 0; nt < 4; ++nt)
            MuA[qr * 148 + nt * 32 + l31] = (__bf16)accM[nt][r];
        if (l31 == 0) MuA[qr * 148 + 128] = (__bf16)mu128p[r];
        if (l31 >= 1 && l31 <= 15) MuA[qr * 148 + 128 + l31] = (__bf16)0.f;
    }
    bf16x8 Ah[9];
    #pragma unroll
    for (int ks = 0; ks < 9; ++ks) Ah[ks] = ld_lds8(MuA + l31 * 148 + ks * 16 + half * 8);
    #pragma unroll
    for (int r = 0; r < 16; ++r) {
        const int qr = (r & 3) + 8 * (r >> 2) + 4 * half;
        #pragma unroll
        for (int nt = 0; nt < 4; ++nt) {
            float m = accM[nt][r];
            MuA[qr * 148 + nt * 32 + l31] = (__bf16)(m - (float)(__bf16)m);
        }
        if (l31 == 0) {
            float m = mu128p[r];
            MuA[qr * 148 + 128] = (__bf16)(m - (float)(__bf16)m);
        }
    }
    bf16x8 Al[9];
    #pragma unroll
    for (int ks = 0; ks < 9; ++ks) Al[ks] = ld_lds8(MuA + l31 * 148 + ks * 16 + half * 8);

    f32x16 accU[4] = {};
    #pragma unroll
    for (int ks = 0; ks < 9; ++ks) {
        #pragma unroll
        for (int nt = 0; nt < 4; ++nt) {
            bf16x8 bh = *(const bf16x8*)(Woh + (size_t)(nt * 32 + l31) * 144 + ks * 16 + half * 8);
            bf16x8 bl = *(const bf16x8*)(Wol + (size_t)(nt * 32 + l31) * 144 + ks * 16 + half * 8);
            accU[nt] = MFMA(Ah[ks], bh, accU[nt]);
            accU[nt] = MFMA(Ah[ks], bl, accU[nt]);
            accU[nt] = MFMA(Al[ks], bh, accU[nt]);
        }
    }

    float bov[4];
    #pragma unroll
    for (int nt = 0; nt < 4; ++nt) bov[nt] = bo[nt * 32 + l31];
    #pragma unroll
    for (int r = 0; r < 16; ++r) {
        float p = 0.f;
        #pragma unroll
        for (int nt = 0; nt < 4; ++nt) {
            float uv = accU[nt][r] + bov[nt];
            accU[nt][r] = uv;
            p += uv * uv;
        }
        float nn = half_sum32(p, half);
        float nu = fmaxf(sqrtf(nn), 1e-7f);
        float aa = SCf * nu;
        float cf = tanhf(aa) / aa;
        const int qr = (r & 3) + 8 * (r >> 2) + 4 * half;
        const size_t row = (size_t)(b * N_ + qb + w * 32 + qr);
        #pragma unroll
        for (int nt = 0; nt < 4; ++nt)
            Y[row * D_ + nt * 32 + l31] = accU[nt][r] * cf;
        if (l31 == 0) Y2[row] = nn * cf * cf;
    }
}

// ---------------- diagonal Gram blocks: G[b][c][i][k] = <y_i, y_k>, i,k in chunk c ----------------
__global__ __launch_bounds__(256) void k_gram(const float* __restrict__ Y,
                                              float* __restrict__ G) {
    const int c = blockIdx.x, b = blockIdx.y;
    const int t = threadIdx.x, w = t >> 6, l = t & 63;
    const int l31 = l & 31, half = l >> 5;
    const int rt = w >> 1, ct = w & 1;                 // 32x32 tile of the 64x64 block
    const size_t base = (size_t)(b * N_ + c * 64);
    const float* Ar = Y + (base + rt * 32 + l31) * D_;
    const float* Br = Y + (base + ct * 32 + l31) * D_;
    f32x16 acc = {};
    #pragma unroll
    for (int ks = 0; ks < 8; ++ks) {
        const int c0 = ks * 16 + half * 8;
        float4 a0 = *(const float4*)(Ar + c0);
        float4 a1 = *(const float4*)(Ar + c0 + 4);
        float4 b0 = *(const float4*)(Br + c0);
        float4 b1 = *(const float4*)(Br + c0 + 4);
        float av[8] = {a0.x, a0.y, a0.z, a0.w, a1.x, a1.y, a1.z, a1.w};
        float bv[8] = {b0.x, b0.y, b0.z, b0.w, b1.x, b1.y, b1.z, b1.w};
        bf16x8 ah, al, bh, bl;
        #pragma unroll
        for (int j = 0; j < 8; ++j) {
            __bf16 h = (__bf16)av[j]; ah[j] = h; al[j] = (__bf16)(av[j] - (float)h);
            __bf16 g = (__bf16)bv[j]; bh[j] = g; bl[j] = (__bf16)(bv[j] - (float)g);
        }
        acc = MFMA(ah, bh, acc);
        acc = MFMA(ah, bl, acc);
        acc = MFMA(al, bh, acc);
    }
    float* Gb = G + ((size_t)(b * 16 + c) << 12);
    #pragma unroll
    for (int r = 0; r < 16; ++r) {
        const int row = rt * 32 + (r & 3) + 8 * (r >> 2) + 4 * half;
        Gb[row * 64 + ct * 32 + l31] = acc[r];
    }
}

// ---------------- Mobius fold: Gram-scan (readlane chain, f32 homogeneous state) ----------------
// acc = U/Dh, x2 = P/Dh^2.  g_k = <U, y_k> obeys g_k <- Af*g_k + Bf*G[i][k]; puy = readlane(g, i).
// Exact power-of-2 rescale folded into Af/Bf every step (lossless).
__global__ __launch_bounds__(64) void k_pool(const float* __restrict__ Y,
                                             const float* __restrict__ Y2,
                                             const float* __restrict__ G,
                                             const int* __restrict__ mask,
                                             const int* __restrict__ mflag,
                                             const float* __restrict__ Wf,
                                             const float* __restrict__ bf_,
                                             float* __restrict__ out) {
    __shared__ float         py2s[N_];
    __shared__ unsigned char ms[N_];
    __shared__ float         prt[64][65];
    __shared__ double        vb[D_];
    const int b = blockIdx.x, l = threadIdx.x;
    const int is8 = *mflag;

    int cl = 0;
    for (int i = l; i < N_; i += 64) {
        py2s[i] = Y2[b * N_ + i];
        int m = read_mask(mask, is8, b * N_ + i);
        ms[i] = (unsigned char)m;
        cl += m;
    }
    const int cntT = (int)(wave_sum64((float)cl) + 0.5f);
    __syncthreads();

    const float2* __restrict__ Yp = (const float2*)(Y + (size_t)b * N_ * D_) + l;
    const float*  __restrict__ Gp = G + ((size_t)b << 16) + l;   // row r at Gp[r*64]

    constexpr int PF = 16;
    float2 ybuf[PF];
    float  gbuf[PF];
    #pragma unroll
    for (int k = 0; k < PF; ++k) { ybuf[k] = Yp[(size_t)k * 64]; gbuf[k] = Gp[(size_t)k * 64]; }

    float U0 = 0.f, U1 = 0.f, g = 0.f;
    float Dh = 1.f, P = 0.f;

    for (int c = 0; c < 16; ++c) {
        for (int ir0 = 0; ir0 < 64; ir0 += 8) {
            #pragma unroll
            for (int j = 0; j < 8; ++j) {
                const int ir = ir0 + j;
                const int i  = c * 64 + ir;
                const int sl = i & (PF - 1);
                const float2 yv = ybuf[sl];
                const float  Gv = gbuf[sl];
                if (i + PF < N_) {
                    ybuf[sl] = Yp[(size_t)(i + PF) * 64];
                    gbuf[sl] = Gp[(size_t)(i + PF) * 64];
                }
                const float py2 = py2s[i];
                const bool  m   = ms[i] != 0;
                // slack terms (previous-state only)
                const float Dsq   = Dh * Dh;
                const float Bh    = fmaf(-0.1f, P, Dsq);
                const float Donep = Dh * fmaf(0.1f, py2, 1.f);
                const float tP    = (0.01f * py2) * P;
                // critical chain: readlane -> Ahat -> select -> g/U update
                const float puy  = readlane_f(g, ir);
                const float Ahat = fmaf(0.2f, puy, Donep);
                float dh = fmaf(Dh, fmaf(0.2f, puy, Dh), tP);
                dh = fmaxf(dh, 1e-12f * Dsq);
                const float Draw = m ? dh : Dh;
                const int   e    = ilogbf(Draw);          // mant in [1,2)
                const float Am   = m ? Ahat : 1.f;
                const float Bm   = m ? Bh   : 0.f;
                const float Aef  = ldexpf(Am, -e);
                const float Bef  = ldexpf(Bm, -e);
                const float Pn   = fmaf(Am, fmaf(Am, P, (2.f * Bm) * puy), (Bm * Bm) * py2);
                Dh = ldexpf(Draw, -e);
                P  = ldexpf(Pn, -2 * e);
                g  = fmaf(Aef, g, Bef * Gv);
                U0 = fmaf(Aef, U0, Bef * yv.x);
                U1 = fmaf(Aef, U1, Bef * yv.y);
            }
        }
        if (c < 15) {
            // boundary: re-seed g[k] = <U, y_k> for tokens k in chunk c+1
            const int nb = (c + 1) * 64;
            #pragma unroll
            for (int k0 = 0; k0 < 64; k0 += 16) {
                float2 tmp[16];
                #pragma unroll
                for (int k = 0; k < 16; ++k) tmp[k] = Yp[(size_t)(nb + k0 + k) * 64];
                #pragma unroll
                for (int k = 0; k < 16; ++k)
                    prt[k0 + k][l] = fmaf(U0, tmp[k].x, U1 * tmp[k].y);
            }
            float s0 = 0.f, s1 = 0.f, s2 = 0.f, s3 = 0.f;
            #pragma unroll
            for (int p = 0; p < 64; p += 4) {
                s0 += prt[l][p];     s1 += prt[l][p + 1];
                s2 += prt[l][p + 2]; s3 += prt[l][p + 3];
            }
            g = (s0 + s1) + (s2 + s3);
        }
    }

    // de-homogenize + epilogue (f64)
    const double SCd = 0.31622776601683794;
    const double sD = 1.0 / (double)Dh;
    double a0 = sD * (double)U0, a1 = sD * (double)U1;
    double n2 = fmax((double)P * (sD * sD), 0.0);
    double n = sqrt(n2);
    double tt = SCd * n;
    tt = fmin(fmax(tt, 1e-7), 1.0 - 1e-6);
    int cm = cntT > 0 ? cntT : 1;
    float rf = (float)(1.0 / (double)cm);        // ref casts r to float32
    double r = (double)rf;
    double dv = fmax(SCd * n, 1e-7);
    double f = tanh(r * atanh(tt)) / dv;
    double p0 = a0 * f, p1 = a1 * f;
    double q2;
    if (cntT == 0) {                             // fallback: first token's y
        float2 y0v = *(const float2*)(Y + (size_t)(b * N_) * D_ + 2 * l);
        p0 = y0v.x; p1 = y0v.y;
        q2 = (double)Y2[b * N_];
    } else {
        q2 = f * f * n2;
    }
    double npn = fmax(sqrt(q2), 1e-7);
    double t2 = fmin(fmax(SCd * npn, 1e-7), 1.0 - 1e-6);
    double f2 = atanh(t2) / (SCd * npn);
    vb[2 * l]     = p0 * f2;
    vb[2 * l + 1] = p1 * f2;
    __syncthreads();

    if (l < NC_) {
        double o = (double)bf_[l];
        for (int d = 0; d < D_; ++d) o += vb[d] * (double)Wf[l * D_ + d];
        out[b * NC_ + l] = (float)o;
    }
}

extern "C" void kernel_launch(void* const* d_in, const int* in_sizes, int n_in,
                              void* d_out, int out_size, void* d_ws, size_t ws_size,
                              hipStream_t stream) {
    const int*   tok  = (const int*)d_in[0];
    const int*   mask = (const int*)d_in[1];
    const float* emb  = (const float*)d_in[2];
    const float* Wo   = (const float*)d_in[3];
    const float* bo   = (const float*)d_in[4];
    const float* Wf   = (const float*)d_in[5];
    const float* bf_  = (const float*)d_in[6];
    float* out = (float*)d_out;

    char* wsb = (char*)d_ws;
    __bf16* Xh   = (__bf16*)wsb;                              // 16,777,216 B (reused as Gram after k_attn)
    __bf16* Xl   = (__bf16*)(wsb + 16777216);                 // 16,777,216 B
    float*  X0g  = (float*)(wsb + 33554432);                  //    262,144 B
    float*  X128g= (float*)(wsb + 33816576);                  //    262,144 B
    __bf16* Woh  = (__bf16*)(wsb + 34078720);                 //     36,864 B
    __bf16* Wol  = (__bf16*)(wsb + 34115584);                 //     36,864 B
    float*  Y    = (float*)(wsb + 34152448);                  // 33,554,432 B
    float*  Y2   = (float*)(wsb + 67706880);                  //    262,144 B
    int*    flag = (int*)(wsb + 67969024);                    // total ~67.97 MB
    float*  Gram = (float*)wsb;                               // aliases Xh (dead after k_attn): 16.77 MB

    k_detect_mask<<<dim3(1), dim3(256), 0, stream>>>(mask, flag);
    k_prep_wo<<<dim3(72), dim3(256), 0, stream>>>(Wo, Woh, Wol);
    k_prep<<<dim3(B_ * N_ / 64), dim3(256), 0, stream>>>(tok, emb, Xh, Xl, X0g, X128g);
    k_attn<<<dim3(N_ / QB, B_), dim3(256), 53760, stream>>>(Xh, Xl, X0g, X128g, mask, flag,
                                                            Woh, Wol, bo, Y, Y2);
    k_gram<<<dim3(16, B_), dim3(256), 0, stream>>>(Y, Gram);
    k_pool<<<dim3(B_), dim3(64), 0, stream>>>(Y, Y2, Gram, mask, flag, Wf, bf_, out);
}

// Round 7
// 527.098 us; speedup vs baseline: 1.3953x; 1.3953x over previous
//
#include <hip/hip_runtime.h>
#include <math.h>

#define B_    64
#define N_    1024
#define D_    128
#define DP1   129
#define NC_   10
#define QB    128     // queries per block (4 waves x 32)
#define KT    32      // key tile
#define SCf   0.31622776601683794f
#define SCALE 0.08804509063256238f   // 1/sqrt(129)

typedef __bf16 bf16x8 __attribute__((ext_vector_type(8)));
typedef float  f32x16 __attribute__((ext_vector_type(16)));

#define MFMA(a, b, c) __builtin_amdgcn_mfma_f32_32x32x16_bf16((a), (b), (c), 0, 0, 0)

static __device__ __forceinline__ float dpp_add_step(float f, int ctrl, int rmask) {
    if (ctrl == 0x111) { int t = __builtin_amdgcn_update_dpp(0, __builtin_bit_cast(int, f), 0x111, 0xf, 0xf, true); return f + __builtin_bit_cast(float, t); }
    if (ctrl == 0x112) { int t = __builtin_amdgcn_update_dpp(0, __builtin_bit_cast(int, f), 0x112, 0xf, 0xf, true); return f + __builtin_bit_cast(float, t); }
    if (ctrl == 0x114) { int t = __builtin_amdgcn_update_dpp(0, __builtin_bit_cast(int, f), 0x114, 0xf, 0xf, true); return f + __builtin_bit_cast(float, t); }
    if (ctrl == 0x118) { int t = __builtin_amdgcn_update_dpp(0, __builtin_bit_cast(int, f), 0x118, 0xf, 0xf, true); return f + __builtin_bit_cast(float, t); }
    if (ctrl == 0x142 && rmask == 0xa) { int t = __builtin_amdgcn_update_dpp(0, __builtin_bit_cast(int, f), 0x142, 0xa, 0xf, true); return f + __builtin_bit_cast(float, t); }
    { int t = __builtin_amdgcn_update_dpp(0, __builtin_bit_cast(int, f), 0x143, 0xc, 0xf, true); return f + __builtin_bit_cast(float, t); }
}

// full 64-lane sum, result broadcast to all lanes
static __device__ __forceinline__ float wave_sum64(float f) {
    f = dpp_add_step(f, 0x111, 0xf);
    f = dpp_add_step(f, 0x112, 0xf);
    f = dpp_add_step(f, 0x114, 0xf);
    f = dpp_add_step(f, 0x118, 0xf);
    f = dpp_add_step(f, 0x142, 0xa);
    f = dpp_add_step(f, 0x143, 0xc);
    return __builtin_bit_cast(float, __builtin_amdgcn_readlane(__builtin_bit_cast(int, f), 63));
}

// per-32-lane-half sum, each lane gets its half's total
static __device__ __forceinline__ float half_sum32(float f, int half) {
    f = dpp_add_step(f, 0x111, 0xf);
    f = dpp_add_step(f, 0x112, 0xf);
    f = dpp_add_step(f, 0x114, 0xf);
    f = dpp_add_step(f, 0x118, 0xf);
    f = dpp_add_step(f, 0x142, 0xa);
    float s0 = __builtin_bit_cast(float, __builtin_amdgcn_readlane(__builtin_bit_cast(int, f), 31));
    float s1 = __builtin_bit_cast(float, __builtin_amdgcn_readlane(__builtin_bit_cast(int, f), 63));
    return half ? s1 : s0;
}

static __device__ __forceinline__ float readlane_f(float v, int lane) {
    return __builtin_bit_cast(float, __builtin_amdgcn_readlane(__builtin_bit_cast(int, v), lane));
}

static __device__ __forceinline__ bf16x8 ld_lds8(const __bf16* p) {
    union { bf16x8 v; unsigned long long q[2]; } u;
    u.q[0] = *(const unsigned long long*)(p);
    u.q[1] = *(const unsigned long long*)(p + 4);
    return u.v;
}

// ---------------- mask dtype detection (int32 vs packed int8 bool) ----------------
__global__ __launch_bounds__(256) void k_detect_mask(const int* __restrict__ mask_w,
                                                     int* __restrict__ flag) {
    __shared__ int bad;
    if (threadIdx.x == 0) bad = 0;
    __syncthreads();
    int local = 0;
    for (int i = threadIdx.x; i < 16384; i += 256) {
        int v = mask_w[i];
        if (v != 0 && v != 1) local = 1;
    }
    if (local) atomicOr(&bad, 1);
    __syncthreads();
    if (threadIdx.x == 0) *flag = bad;   // 1 => data is packed int8 bools
}

static __device__ __forceinline__ int read_mask(const int* mw, int is_i8, int idx) {
    if (is_i8) return (int)((const unsigned char*)mw)[idx];
    return mw[idx];
}

// ---------------- Wo -> bf16 hi/lo, layout [o][144] (K padded 129->144 with zeros) ----------------
__global__ __launch_bounds__(256) void k_prep_wo(const float* __restrict__ Wo,
                                                 __bf16* __restrict__ Woh,
                                                 __bf16* __restrict__ Wol) {
    int idx = blockIdx.x * 256 + threadIdx.x;
    if (idx >= 128 * 144) return;
    int o = idx / 144, d = idx - o * 144;
    float v = (d < DP1) ? Wo[o * DP1 + d] : 0.f;
    __bf16 h = (__bf16)v;
    Woh[idx] = h;
    Wol[idx] = (__bf16)(v - (float)h);
}

// ---------------- embedding + Lorentz expmap0 -> bf16 hi/lo rows + comp0/comp128 f32 ----------------
__global__ __launch_bounds__(256) void k_prep(const int* __restrict__ tok,
                                              const float* __restrict__ emb,
                                              __bf16* __restrict__ Xh, __bf16* __restrict__ Xl,
                                              float* __restrict__ X0g, float* __restrict__ X128g) {
    __shared__ float Xf[64][132];
    const int t = threadIdx.x, w = t >> 6, l = t & 63;
    const int base = blockIdx.x * 64;
    for (int it = 0; it < 16; ++it) {
        const int tk = w * 16 + it;
        const int id = tok[base + tk];
        const float2 v = ((const float2*)(emb + (size_t)id * D_))[l];
        float s = wave_sum64(v.x * v.x + v.y * v.y);
        float nv = fmaxf(sqrtf(s), 1e-7f);
        float a = SCf * nv;
        float a2 = a * a;
        float shc, ch;
        if (a < 0.5f) {
            shc = 1.f + a2 * (1.f/6.f) * (1.f + a2 * (1.f/20.f) * (1.f + a2 * (1.f/42.f)));
            ch  = 1.f + a2 * 0.5f * (1.f + a2 * (1.f/12.f) * (1.f + a2 * (1.f/30.f)));
        } else {
            float ea = __expf(a), ei = 1.f / ea;
            ch = 0.5f * (ea + ei);
            shc = 0.5f * (ea - ei) / a;
        }
        Xf[tk][1 + 2 * l] = v.x * shc;
        Xf[tk][2 + 2 * l] = v.y * shc;
        if (l == 0) Xf[tk][0] = ch / SCf;
    }
    __syncthreads();
    const int tk2 = t >> 2, dg = (t & 3) * 32;
    for (int i = 0; i < 32; i += 8) {
        bf16x8 hv, lv;
        #pragma unroll
        for (int j = 0; j < 8; ++j) {
            float f = Xf[tk2][dg + i + j];
            __bf16 h = (__bf16)f;
            hv[j] = h;
            lv[j] = (__bf16)(f - (float)h);
        }
        *(bf16x8*)(Xh + (size_t)(base + tk2) * D_ + dg + i) = hv;
        *(bf16x8*)(Xl + (size_t)(base + tk2) * D_ + dg + i) = lv;
    }
    if (t < 64) {
        X0g[base + t]   = Xf[t][0];
        X128g[base + t] = Xf[t][D_];
    }
}

// ---------------- fused MFMA attention: scores + exp + centroid + renorm + projection + expmap ----------------
__global__ __launch_bounds__(256, 2) void k_attn(
        const __bf16* __restrict__ Xh, const __bf16* __restrict__ Xl,
        const float* __restrict__ X0g, const float* __restrict__ X128g,
        const int* __restrict__ mask, const int* __restrict__ mflag,
        const __bf16* __restrict__ Woh, const __bf16* __restrict__ Wol,
        const float* __restrict__ bo,
        float* __restrict__ Y, float* __restrict__ Y2) {
    extern __shared__ char smem[];
    __bf16* Krow = (__bf16*)smem;                   // 16896 B
    __bf16* XTb  = (__bf16*)(smem + 16896);         // 18432 B
    __bf16* Pb   = (__bf16*)(smem + 35328);         // 18432 B
    __shared__ float K0s[KT];
    __shared__ float K128s[KT];
    __shared__ int   Ms[KT];

    const int b    = blockIdx.y;
    const int qb   = blockIdx.x * QB;
    const int t    = threadIdx.x;
    const int w    = t >> 6;
    const int l    = t & 63;
    const int l31  = l & 31;
    const int half = l >> 5;
    const int is8  = *mflag;

    const size_t qrow = (size_t)(b * N_ + qb + w * 32 + l31);
    bf16x8 qfh[8], qfl[8];
    #pragma unroll
    for (int ks = 0; ks < 8; ++ks) {
        qfh[ks] = *(const bf16x8*)(Xh + qrow * D_ + ks * 16 + half * 8);
        qfl[ks] = *(const bf16x8*)(Xl + qrow * D_ + ks * 16 + half * 8);
    }
    float q0[16], q128[16];
    #pragma unroll
    for (int r = 0; r < 16; ++r) {
        const int qr = (r & 3) + 8 * (r >> 2) + 4 * half;
        q0[r]   = X0g[b * N_ + qb + w * 32 + qr];
        q128[r] = X128g[b * N_ + qb + w * 32 + qr];
    }

    f32x16 accM[4] = {};
    float  mu128p[16] = {};

    for (int kt = 0; kt < N_ / KT; ++kt) {
        __syncthreads();
        {
            const int key = t >> 3, ck = t & 7;
            const size_t krow = (size_t)(b * N_ + kt * KT + key);
            #pragma unroll
            for (int ch = 0; ch < 2; ++ch) {
                const int c0 = ck * 8 + 64 * ch;
                bf16x8 vh = *(const bf16x8*)(Xh + krow * D_ + c0);
                bf16x8 vl = *(const bf16x8*)(Xl + krow * D_ + c0);
                union { bf16x8 v; unsigned long long q[2]; } uh, ul;
                uh.v = vh; ul.v = vl;
                *(unsigned long long*)(Krow + key * 132 + c0)            = uh.q[0];
                *(unsigned long long*)(Krow + key * 132 + c0 + 4)        = uh.q[1];
                *(unsigned long long*)(Krow + 4224 + key * 132 + c0)     = ul.q[0];
                *(unsigned long long*)(Krow + 4224 + key * 132 + c0 + 4) = ul.q[1];
                #pragma unroll
                for (int j = 0; j < 8; ++j) {
                    XTb[(c0 + j) * 36 + key]        = vh[j];
                    XTb[4608 + (c0 + j) * 36 + key] = vl[j];
                }
            }
            if (t < KT) {
                K0s[t]   = X0g[b * N_ + kt * KT + t];
                K128s[t] = X128g[b * N_ + kt * KT + t];
                Ms[t]    = read_mask(mask, is8, b * N_ + kt * KT + t);
            }
        }
        __syncthreads();

        f32x16 accS = {};
        #pragma unroll
        for (int ks = 0; ks < 8; ++ks) {
            bf16x8 bh = ld_lds8(Krow + l31 * 132 + ks * 16 + half * 8);
            bf16x8 bl = ld_lds8(Krow + 4224 + l31 * 132 + ks * 16 + half * 8);
            accS = MFMA(qfh[ks], bh, accS);
            accS = MFMA(qfh[ks], bl, accS);
            accS = MFMA(qfl[ks], bh, accS);
        }
        const float k0v = K0s[l31], k128v = K128s[l31];
        const int   mv  = Ms[l31];
        #pragma unroll
        for (int r = 0; r < 16; ++r) {
            float sc = (2.f * q0[r] * k0v - accS[r] - q128[r] * k128v) * SCALE;
            float e  = mv ? __expf(sc) : 0.f;
            mu128p[r] += e * k128v;
            __bf16 eh = (__bf16)e;
            __bf16 el = (__bf16)(e - (float)eh);
            const int qr = (r & 3) + 8 * (r >> 2) + 4 * half;
            Pb[(w * 2 + 0) * 1152 + qr * 36 + l31] = eh;
            Pb[(w * 2 + 1) * 1152 + qr * 36 + l31] = el;
        }

        #pragma unroll
        for (int ks = 0; ks < 2; ++ks) {
            bf16x8 ah = ld_lds8(Pb + (w * 2 + 0) * 1152 + l31 * 36 + ks * 16 + half * 8);
            bf16x8 al = ld_lds8(Pb + (w * 2 + 1) * 1152 + l31 * 36 + ks * 16 + half * 8);
            #pragma unroll
            for (int nt = 0; nt < 4; ++nt) {
                bf16x8 bh = ld_lds8(XTb + (nt * 32 + l31) * 36 + ks * 16 + half * 8);
                bf16x8 bl = ld_lds8(XTb + 4608 + (nt * 32 + l31) * 36 + ks * 16 + half * 8);
                accM[nt] = MFMA(ah, bh, accM[nt]);
                accM[nt] = MFMA(ah, bl, accM[nt]);
                accM[nt] = MFMA(al, bh, accM[nt]);
            }
        }
    }

    #pragma unroll
    for (int r = 0; r < 16; ++r) mu128p[r] = half_sum32(mu128p[r], half);
    float rno[16];
    #pragma unroll
    for (int r = 0; r < 16; ++r) {
        float p = 0.f;
        #pragma unroll
        for (int nt = 0; nt < 4; ++nt) p += accM[nt][r] * accM[nt][r];
        if (l31 == 0) p -= 2.f * accM[0][r] * accM[0][r];
        p = half_sum32(p, half);
        float negI = -(p + mu128p[r] * mu128p[r]);
        negI = fmaxf(negI, 1e-7f);
        rno[r] = 1.f / (SCf * sqrtf(negI));
    }
    #pragma unroll
    for (int nt = 0; nt < 4; ++nt)
        #pragma unroll
        for (int r = 0; r < 16; ++r) accM[nt][r] *= rno[r];
    #pragma unroll
    for (int r = 0; r < 16; ++r) mu128p[r] *= rno[r];

    __syncthreads();
    __bf16* MuA = (__bf16*)smem + w * (32 * 148);
    #pragma unroll
    for (int r = 0; r < 16; ++r) {
        const int qr = (r & 3) + 8 * (r >> 2) + 4 * half;
        #pragma unroll
        for (int nt = 0; nt < 4; ++nt)
            MuA[qr * 148 + nt * 32 + l31] = (__bf16)accM[nt][r];
        if (l31 == 0) MuA[qr * 148 + 128] = (__bf16)mu128p[r];
        if (l31 >= 1 && l31 <= 15) MuA[qr * 148 + 128 + l31] = (__bf16)0.f;
    }
    bf16x8 Ah[9];
    #pragma unroll
    for (int ks = 0; ks < 9; ++ks) Ah[ks] = ld_lds8(MuA + l31 * 148 + ks * 16 + half * 8);
    #pragma unroll
    for (int r = 0; r < 16; ++r) {
        const int qr = (r & 3) + 8 * (r >> 2) + 4 * half;
        #pragma unroll
        for (int nt = 0; nt < 4; ++nt) {
            float m = accM[nt][r];
            MuA[qr * 148 + nt * 32 + l31] = (__bf16)(m - (float)(__bf16)m);
        }
        if (l31 == 0) {
            float m = mu128p[r];
            MuA[qr * 148 + 128] = (__bf16)(m - (float)(__bf16)m);
        }
    }
    bf16x8 Al[9];
    #pragma unroll
    for (int ks = 0; ks < 9; ++ks) Al[ks] = ld_lds8(MuA + l31 * 148 + ks * 16 + half * 8);

    f32x16 accU[4] = {};
    #pragma unroll
    for (int ks = 0; ks < 9; ++ks) {
        #pragma unroll
        for (int nt = 0; nt < 4; ++nt) {
            bf16x8 bh = *(const bf16x8*)(Woh + (size_t)(nt * 32 + l31) * 144 + ks * 16 + half * 8);
            bf16x8 bl = *(const bf16x8*)(Wol + (size_t)(nt * 32 + l31) * 144 + ks * 16 + half * 8);
            accU[nt] = MFMA(Ah[ks], bh, accU[nt]);
            accU[nt] = MFMA(Ah[ks], bl, accU[nt]);
            accU[nt] = MFMA(Al[ks], bh, accU[nt]);
        }
    }

    float bov[4];
    #pragma unroll
    for (int nt = 0; nt < 4; ++nt) bov[nt] = bo[nt * 32 + l31];
    #pragma unroll
    for (int r = 0; r < 16; ++r) {
        float p = 0.f;
        #pragma unroll
        for (int nt = 0; nt < 4; ++nt) {
            float uv = accU[nt][r] + bov[nt];
            accU[nt][r] = uv;
            p += uv * uv;
        }
        float nn = half_sum32(p, half);
        float nu = fmaxf(sqrtf(nn), 1e-7f);
        float aa = SCf * nu;
        float cf = tanhf(aa) / aa;
        const int qr = (r & 3) + 8 * (r >> 2) + 4 * half;
        const size_t row = (size_t)(b * N_ + qb + w * 32 + qr);
        #pragma unroll
        for (int nt = 0; nt < 4; ++nt)
            Y[row * D_ + nt * 32 + l31] = accU[nt][r] * cf;
        if (l31 == 0) Y2[row] = nn * cf * cf;
    }
}

// ---------------- diagonal Gram blocks: G[b][c][i][k] = <y_i, y_k>, i,k in chunk c ----------------
__global__ __launch_bounds__(256) void k_gram(const float* __restrict__ Y,
                                              float* __restrict__ G) {
    const int c = blockIdx.x, b = blockIdx.y;
    const int t = threadIdx.x, w = t >> 6, l = t & 63;
    const int l31 = l & 31, half = l >> 5;
    const int rt = w >> 1, ct = w & 1;                 // 32x32 tile of the 64x64 block
    const size_t base = (size_t)(b * N_ + c * 64);
    const float* Ar = Y + (base + rt * 32 + l31) * D_;
    const float* Br = Y + (base + ct * 32 + l31) * D_;
    f32x16 acc = {};
    #pragma unroll
    for (int ks = 0; ks < 8; ++ks) {
        const int c0 = ks * 16 + half * 8;
        float4 a0 = *(const float4*)(Ar + c0);
        float4 a1 = *(const float4*)(Ar + c0 + 4);
        float4 b0 = *(const float4*)(Br + c0);
        float4 b1 = *(const float4*)(Br + c0 + 4);
        float av[8] = {a0.x, a0.y, a0.z, a0.w, a1.x, a1.y, a1.z, a1.w};
        float bv[8] = {b0.x, b0.y, b0.z, b0.w, b1.x, b1.y, b1.z, b1.w};
        bf16x8 ah, al, bh, bl;
        #pragma unroll
        for (int j = 0; j < 8; ++j) {
            __bf16 h = (__bf16)av[j]; ah[j] = h; al[j] = (__bf16)(av[j] - (float)h);
            __bf16 g = (__bf16)bv[j]; bh[j] = g; bl[j] = (__bf16)(bv[j] - (float)g);
        }
        acc = MFMA(ah, bh, acc);
        acc = MFMA(ah, bl, acc);
        acc = MFMA(al, bh, acc);
    }
    float* Gb = G + ((size_t)(b * 16 + c) << 12);
    #pragma unroll
    for (int r = 0; r < 16; ++r) {
        const int row = rt * 32 + (r & 3) + 8 * (r >> 2) + 4 * half;
        Gb[row * 64 + ct * 32 + l31] = acc[r];
    }
}

// ---------------- Mobius fold: Gram-scan (readlane chain, f32 homogeneous state) ----------------
// acc = U/Dh, x2 = P/Dh^2.  g_k = <U, y_k> obeys g_k <- Af*g_k + Bf*G[i][k]; puy = readlane(g, i).
// Exact power-of-2 rescale folded into Af/Bf every step (lossless).
// NOTE: ring-buffer indices MUST be compile-time constants (k) or the arrays spill to scratch
// (round-6 regression: dynamic `i & 15` index -> private-memory round-trips, 470 us).
__global__ __launch_bounds__(64) void k_pool(const float* __restrict__ Y,
                                             const float* __restrict__ Y2,
                                             const float* __restrict__ G,
                                             const int* __restrict__ mask,
                                             const int* __restrict__ mflag,
                                             const float* __restrict__ Wf,
                                             const float* __restrict__ bf_,
                                             float* __restrict__ out) {
    __shared__ float         py2s[N_];
    __shared__ unsigned char ms[N_];
    __shared__ float         prt[64][65];
    __shared__ double        vb[D_];
    const int b = blockIdx.x, l = threadIdx.x;
    const int is8 = *mflag;

    int cl = 0;
    for (int i = l; i < N_; i += 64) {
        py2s[i] = Y2[b * N_ + i];
        int m = read_mask(mask, is8, b * N_ + i);
        ms[i] = (unsigned char)m;
        cl += m;
    }
    const int cntT = (int)(wave_sum64((float)cl) + 0.5f);
    __syncthreads();

    const float2* __restrict__ Yp = (const float2*)(Y + (size_t)b * N_ * D_) + l;
    const float*  __restrict__ Gp = G + ((size_t)b << 16) + l;   // token i's row at Gp[i*64]

    constexpr int PF = 16;
    float2 ybuf[PF];
    float  gbuf[PF];
    #pragma unroll
    for (int k = 0; k < PF; ++k) { ybuf[k] = Yp[(size_t)k * 64]; gbuf[k] = Gp[(size_t)k * 64]; }

    float U0 = 0.f, U1 = 0.f, g = 0.f;
    float Dh = 1.f, P = 0.f;

    for (int c = 0; c < 16; ++c) {
        #pragma unroll
        for (int q = 0; q < 4; ++q) {
            #pragma unroll
            for (int k = 0; k < PF; ++k) {         // ring index k: compile-time!
                const int ir = q * PF + k;         // lane index: compile-time constant
                const int i  = c * 64 + ir;
                const float2 yv = ybuf[k];
                const float  Gv = gbuf[k];
                if (i + PF < N_) {
                    ybuf[k] = Yp[(size_t)(i + PF) * 64];
                    gbuf[k] = Gp[(size_t)(i + PF) * 64];
                }
                const float py2 = py2s[i];
                const bool  m   = ms[i] != 0;
                // slack terms (previous-state only)
                const float Dsq   = Dh * Dh;
                const float Bh    = fmaf(-0.1f, P, Dsq);
                const float Donep = Dh * fmaf(0.1f, py2, 1.f);
                const float tP    = (0.01f * py2) * P;
                // critical chain: readlane -> Ahat -> select -> frexp/ldexp -> g/U update
                const float puy  = readlane_f(g, ir);
                const float Ahat = fmaf(0.2f, puy, Donep);
                float dh = fmaf(Dh, fmaf(0.2f, puy, Dh), tP);
                dh = fmaxf(dh, 1e-12f * Dsq);
                const float Draw = m ? dh : Dh;
                const int   e    = ilogbf(Draw);
                const float Am   = m ? Ahat : 1.f;
                const float Bm   = m ? Bh   : 0.f;
                const float Aef  = ldexpf(Am, -e);
                const float Bef  = ldexpf(Bm, -e);
                const float Pn   = fmaf(Am, fmaf(Am, P, (2.f * Bm) * puy), (Bm * Bm) * py2);
                Dh = ldexpf(Draw, -e);
                P  = ldexpf(Pn, -2 * e);
                g  = fmaf(Aef, g, Bef * Gv);
                U0 = fmaf(Aef, U0, Bef * yv.x);
                U1 = fmaf(Aef, U1, Bef * yv.y);
            }
        }
        if (c < 15) {
            // boundary: re-seed g[k] = <U, y_k> for tokens k in chunk c+1
            const int nb = (c + 1) * 64;
            #pragma unroll
            for (int k0 = 0; k0 < 64; k0 += 16) {
                float2 tmp[16];
                #pragma unroll
                for (int k = 0; k < 16; ++k) tmp[k] = Yp[(size_t)(nb + k0 + k) * 64];
                #pragma unroll
                for (int k = 0; k < 16; ++k)
                    prt[k0 + k][l] = fmaf(U0, tmp[k].x, U1 * tmp[k].y);
            }
            float s0 = 0.f, s1 = 0.f, s2 = 0.f, s3 = 0.f;
            #pragma unroll
            for (int p = 0; p < 64; p += 4) {
                s0 += prt[l][p];     s1 += prt[l][p + 1];
                s2 += prt[l][p + 2]; s3 += prt[l][p + 3];
            }
            g = (s0 + s1) + (s2 + s3);
        }
    }

    // de-homogenize + epilogue (f64)
    const double SCd = 0.31622776601683794;
    const double sD = 1.0 / (double)Dh;
    double a0 = sD * (double)U0, a1 = sD * (double)U1;
    double n2 = fmax((double)P * (sD * sD), 0.0);
    double n = sqrt(n2);
    double tt = SCd * n;
    tt = fmin(fmax(tt, 1e-7), 1.0 - 1e-6);
    int cm = cntT > 0 ? cntT : 1;
    float rf = (float)(1.0 / (double)cm);        // ref casts r to float32
    double r = (double)rf;
    double dv = fmax(SCd * n, 1e-7);
    double f = tanh(r * atanh(tt)) / dv;
    double p0 = a0 * f, p1 = a1 * f;
    double q2;
    if (cntT == 0) {                             // fallback: first token's y
        float2 y0v = *(const float2*)(Y + (size_t)(b * N_) * D_ + 2 * l);
        p0 = y0v.x; p1 = y0v.y;
        q2 = (double)Y2[b * N_];
    } else {
        q2 = f * f * n2;
    }
    double npn = fmax(sqrt(q2), 1e-7);
    double t2 = fmin(fmax(SCd * npn, 1e-7), 1.0 - 1e-6);
    double f2 = atanh(t2) / (SCd * npn);
    vb[2 * l]     = p0 * f2;
    vb[2 * l + 1] = p1 * f2;
    __syncthreads();

    if (l < NC_) {
        double o = (double)bf_[l];
        for (int d = 0; d < D_; ++d) o += vb[d] * (double)Wf[l * D_ + d];
        out[b * NC_ + l] = (float)o;
    }
}

extern "C" void kernel_launch(void* const* d_in, const int* in_sizes, int n_in,
                              void* d_out, int out_size, void* d_ws, size_t ws_size,
                              hipStream_t stream) {
    const int*   tok  = (const int*)d_in[0];
    const int*   mask = (const int*)d_in[1];
    const float* emb  = (const float*)d_in[2];
    const float* Wo   = (const float*)d_in[3];
    const float* bo   = (const float*)d_in[4];
    const float* Wf   = (const float*)d_in[5];
    const float* bf_  = (const float*)d_in[6];
    float* out = (float*)d_out;

    char* wsb = (char*)d_ws;
    __bf16* Xh   = (__bf16*)wsb;                              // 16,777,216 B (reused as Gram after k_attn)
    __bf16* Xl   = (__bf16*)(wsb + 16777216);                 // 16,777,216 B
    float*  X0g  = (float*)(wsb + 33554432);                  //    262,144 B
    float*  X128g= (float*)(wsb + 33816576);                  //    262,144 B
    __bf16* Woh  = (__bf16*)(wsb + 34078720);                 //     36,864 B
    __bf16* Wol  = (__bf16*)(wsb + 34115584);                 //     36,864 B
    float*  Y    = (float*)(wsb + 34152448);                  // 33,554,432 B
    float*  Y2   = (float*)(wsb + 67706880);                  //    262,144 B
    int*    flag = (int*)(wsb + 67969024);                    // total ~67.97 MB
    float*  Gram = (float*)wsb;                               // aliases Xh (dead after k_attn): 16.77 MB

    k_detect_mask<<<dim3(1), dim3(256), 0, stream>>>(mask, flag);
    k_prep_wo<<<dim3(72), dim3(256), 0, stream>>>(Wo, Woh, Wol);
    k_prep<<<dim3(B_ * N_ / 64), dim3(256), 0, stream>>>(tok, emb, Xh, Xl, X0g, X128g);
    k_attn<<<dim3(N_ / QB, B_), dim3(256), 53760, stream>>>(Xh, Xl, X0g, X128g, mask, flag,
                                                            Woh, Wol, bo, Y, Y2);
    k_gram<<<dim3(16, B_), dim3(256), 0, stream>>>(Y, Gram);
    k_pool<<<dim3(B_), dim3(64), 0, stream>>>(Y, Y2, Gram, mask, flag, Wf, bf_, out);
}

// Round 8
// 402.768 us; speedup vs baseline: 1.8260x; 1.3087x over previous
//
#include <hip/hip_runtime.h>
#include <math.h>

#define B_    64
#define N_    1024
#define D_    128
#define DP1   129
#define NC_   10
#define QB    128     // queries per block (4 waves x 32)
#define KT    32      // key tile
#define SCf   0.31622776601683794f
#define SCALE 0.08804509063256238f   // 1/sqrt(129)

typedef __bf16 bf16x8 __attribute__((ext_vector_type(8)));
typedef float  f32x16 __attribute__((ext_vector_type(16)));

#define MFMA(a, b, c) __builtin_amdgcn_mfma_f32_32x32x16_bf16((a), (b), (c), 0, 0, 0)

static __device__ __forceinline__ float dpp_add_step(float f, int ctrl, int rmask) {
    if (ctrl == 0x111) { int t = __builtin_amdgcn_update_dpp(0, __builtin_bit_cast(int, f), 0x111, 0xf, 0xf, true); return f + __builtin_bit_cast(float, t); }
    if (ctrl == 0x112) { int t = __builtin_amdgcn_update_dpp(0, __builtin_bit_cast(int, f), 0x112, 0xf, 0xf, true); return f + __builtin_bit_cast(float, t); }
    if (ctrl == 0x114) { int t = __builtin_amdgcn_update_dpp(0, __builtin_bit_cast(int, f), 0x114, 0xf, 0xf, true); return f + __builtin_bit_cast(float, t); }
    if (ctrl == 0x118) { int t = __builtin_amdgcn_update_dpp(0, __builtin_bit_cast(int, f), 0x118, 0xf, 0xf, true); return f + __builtin_bit_cast(float, t); }
    if (ctrl == 0x142 && rmask == 0xa) { int t = __builtin_amdgcn_update_dpp(0, __builtin_bit_cast(int, f), 0x142, 0xa, 0xf, true); return f + __builtin_bit_cast(float, t); }
    { int t = __builtin_amdgcn_update_dpp(0, __builtin_bit_cast(int, f), 0x143, 0xc, 0xf, true); return f + __builtin_bit_cast(float, t); }
}

// full 64-lane sum, result broadcast to all lanes
static __device__ __forceinline__ float wave_sum64(float f) {
    f = dpp_add_step(f, 0x111, 0xf);
    f = dpp_add_step(f, 0x112, 0xf);
    f = dpp_add_step(f, 0x114, 0xf);
    f = dpp_add_step(f, 0x118, 0xf);
    f = dpp_add_step(f, 0x142, 0xa);
    f = dpp_add_step(f, 0x143, 0xc);
    return __builtin_bit_cast(float, __builtin_amdgcn_readlane(__builtin_bit_cast(int, f), 63));
}

// per-32-lane-half sum, each lane gets its half's total
static __device__ __forceinline__ float half_sum32(float f, int half) {
    f = dpp_add_step(f, 0x111, 0xf);
    f = dpp_add_step(f, 0x112, 0xf);
    f = dpp_add_step(f, 0x114, 0xf);
    f = dpp_add_step(f, 0x118, 0xf);
    f = dpp_add_step(f, 0x142, 0xa);
    float s0 = __builtin_bit_cast(float, __builtin_amdgcn_readlane(__builtin_bit_cast(int, f), 31));
    float s1 = __builtin_bit_cast(float, __builtin_amdgcn_readlane(__builtin_bit_cast(int, f), 63));
    return half ? s1 : s0;
}

static __device__ __forceinline__ float readlane_f(float v, int lane) {
    return __builtin_bit_cast(float, __builtin_amdgcn_readlane(__builtin_bit_cast(int, v), lane));
}

static __device__ __forceinline__ bf16x8 ld_lds8(const __bf16* p) {
    union { bf16x8 v; unsigned long long q[2]; } u;
    u.q[0] = *(const unsigned long long*)(p);
    u.q[1] = *(const unsigned long long*)(p + 4);
    return u.v;
}

// ---------------- mask dtype detection (int32 vs packed int8 bool) ----------------
__global__ __launch_bounds__(256) void k_detect_mask(const int* __restrict__ mask_w,
                                                     int* __restrict__ flag) {
    __shared__ int bad;
    if (threadIdx.x == 0) bad = 0;
    __syncthreads();
    int local = 0;
    for (int i = threadIdx.x; i < 16384; i += 256) {
        int v = mask_w[i];
        if (v != 0 && v != 1) local = 1;
    }
    if (local) atomicOr(&bad, 1);
    __syncthreads();
    if (threadIdx.x == 0) *flag = bad;   // 1 => data is packed int8 bools
}

static __device__ __forceinline__ int read_mask(const int* mw, int is_i8, int idx) {
    if (is_i8) return (int)((const unsigned char*)mw)[idx];
    return mw[idx];
}

// ---------------- Wo -> bf16 hi/lo, layout [o][144] (K padded 129->144 with zeros) ----------------
__global__ __launch_bounds__(256) void k_prep_wo(const float* __restrict__ Wo,
                                                 __bf16* __restrict__ Woh,
                                                 __bf16* __restrict__ Wol) {
    int idx = blockIdx.x * 256 + threadIdx.x;
    if (idx >= 128 * 144) return;
    int o = idx / 144, d = idx - o * 144;
    float v = (d < DP1) ? Wo[o * DP1 + d] : 0.f;
    __bf16 h = (__bf16)v;
    Woh[idx] = h;
    Wol[idx] = (__bf16)(v - (float)h);
}

// ---------------- embedding + Lorentz expmap0 -> bf16 hi/lo rows + comp0/comp128 f32 ----------------
__global__ __launch_bounds__(256) void k_prep(const int* __restrict__ tok,
                                              const float* __restrict__ emb,
                                              __bf16* __restrict__ Xh, __bf16* __restrict__ Xl,
                                              float* __restrict__ X0g, float* __restrict__ X128g) {
    __shared__ float Xf[64][132];
    const int t = threadIdx.x, w = t >> 6, l = t & 63;
    const int base = blockIdx.x * 64;
    for (int it = 0; it < 16; ++it) {
        const int tk = w * 16 + it;
        const int id = tok[base + tk];
        const float2 v = ((const float2*)(emb + (size_t)id * D_))[l];
        float s = wave_sum64(v.x * v.x + v.y * v.y);
        float nv = fmaxf(sqrtf(s), 1e-7f);
        float a = SCf * nv;
        float a2 = a * a;
        float shc, ch;
        if (a < 0.5f) {
            shc = 1.f + a2 * (1.f/6.f) * (1.f + a2 * (1.f/20.f) * (1.f + a2 * (1.f/42.f)));
            ch  = 1.f + a2 * 0.5f * (1.f + a2 * (1.f/12.f) * (1.f + a2 * (1.f/30.f)));
        } else {
            float ea = __expf(a), ei = 1.f / ea;
            ch = 0.5f * (ea + ei);
            shc = 0.5f * (ea - ei) / a;
        }
        Xf[tk][1 + 2 * l] = v.x * shc;
        Xf[tk][2 + 2 * l] = v.y * shc;
        if (l == 0) Xf[tk][0] = ch / SCf;
    }
    __syncthreads();
    const int tk2 = t >> 2, dg = (t & 3) * 32;
    for (int i = 0; i < 32; i += 8) {
        bf16x8 hv, lv;
        #pragma unroll
        for (int j = 0; j < 8; ++j) {
            float f = Xf[tk2][dg + i + j];
            __bf16 h = (__bf16)f;
            hv[j] = h;
            lv[j] = (__bf16)(f - (float)h);
        }
        *(bf16x8*)(Xh + (size_t)(base + tk2) * D_ + dg + i) = hv;
        *(bf16x8*)(Xl + (size_t)(base + tk2) * D_ + dg + i) = lv;
    }
    if (t < 64) {
        X0g[base + t]   = Xf[t][0];
        X128g[base + t] = Xf[t][D_];
    }
}

// ---------------- fused MFMA attention: scores + exp + centroid + renorm + projection + expmap ----------------
__global__ __launch_bounds__(256, 2) void k_attn(
        const __bf16* __restrict__ Xh, const __bf16* __restrict__ Xl,
        const float* __restrict__ X0g, const float* __restrict__ X128g,
        const int* __restrict__ mask, const int* __restrict__ mflag,
        const __bf16* __restrict__ Woh, const __bf16* __restrict__ Wol,
        const float* __restrict__ bo,
        float* __restrict__ Y, float* __restrict__ Y2) {
    extern __shared__ char smem[];
    __bf16* Krow = (__bf16*)smem;                   // 16896 B
    __bf16* XTb  = (__bf16*)(smem + 16896);         // 18432 B
    __bf16* Pb   = (__bf16*)(smem + 35328);         // 18432 B
    __shared__ float K0s[KT];
    __shared__ float K128s[KT];
    __shared__ int   Ms[KT];

    const int b    = blockIdx.y;
    const int qb   = blockIdx.x * QB;
    const int t    = threadIdx.x;
    const int w    = t >> 6;
    const int l    = t & 63;
    const int l31  = l & 31;
    const int half = l >> 5;
    const int is8  = *mflag;

    const size_t qrow = (size_t)(b * N_ + qb + w * 32 + l31);
    bf16x8 qfh[8], qfl[8];
    #pragma unroll
    for (int ks = 0; ks < 8; ++ks) {
        qfh[ks] = *(const bf16x8*)(Xh + qrow * D_ + ks * 16 + half * 8);
        qfl[ks] = *(const bf16x8*)(Xl + qrow * D_ + ks * 16 + half * 8);
    }
    float q0[16], q128[16];
    #pragma unroll
    for (int r = 0; r < 16; ++r) {
        const int qr = (r & 3) + 8 * (r >> 2) + 4 * half;
        q0[r]   = X0g[b * N_ + qb + w * 32 + qr];
        q128[r] = X128g[b * N_ + qb + w * 32 + qr];
    }

    f32x16 accM[4] = {};
    float  mu128p[16] = {};

    for (int kt = 0; kt < N_ / KT; ++kt) {
        __syncthreads();
        {
            const int key = t >> 3, ck = t & 7;
            const size_t krow = (size_t)(b * N_ + kt * KT + key);
            #pragma unroll
            for (int ch = 0; ch < 2; ++ch) {
                const int c0 = ck * 8 + 64 * ch;
                bf16x8 vh = *(const bf16x8*)(Xh + krow * D_ + c0);
                bf16x8 vl = *(const bf16x8*)(Xl + krow * D_ + c0);
                union { bf16x8 v; unsigned long long q[2]; } uh, ul;
                uh.v = vh; ul.v = vl;
                *(unsigned long long*)(Krow + key * 132 + c0)            = uh.q[0];
                *(unsigned long long*)(Krow + key * 132 + c0 + 4)        = uh.q[1];
                *(unsigned long long*)(Krow + 4224 + key * 132 + c0)     = ul.q[0];
                *(unsigned long long*)(Krow + 4224 + key * 132 + c0 + 4) = ul.q[1];
                #pragma unroll
                for (int j = 0; j < 8; ++j) {
                    XTb[(c0 + j) * 36 + key]        = vh[j];
                    XTb[4608 + (c0 + j) * 36 + key] = vl[j];
                }
            }
            if (t < KT) {
                K0s[t]   = X0g[b * N_ + kt * KT + t];
                K128s[t] = X128g[b * N_ + kt * KT + t];
                Ms[t]    = read_mask(mask, is8, b * N_ + kt * KT + t);
            }
        }
        __syncthreads();

        f32x16 accS = {};
        #pragma unroll
        for (int ks = 0; ks < 8; ++ks) {
            bf16x8 bh = ld_lds8(Krow + l31 * 132 + ks * 16 + half * 8);
            bf16x8 bl = ld_lds8(Krow + 4224 + l31 * 132 + ks * 16 + half * 8);
            accS = MFMA(qfh[ks], bh, accS);
            accS = MFMA(qfh[ks], bl, accS);
            accS = MFMA(qfl[ks], bh, accS);
        }
        const float k0v = K0s[l31], k128v = K128s[l31];
        const int   mv  = Ms[l31];
        #pragma unroll
        for (int r = 0; r < 16; ++r) {
            float sc = (2.f * q0[r] * k0v - accS[r] - q128[r] * k128v) * SCALE;
            float e  = mv ? __expf(sc) : 0.f;
            mu128p[r] += e * k128v;
            __bf16 eh = (__bf16)e;
            __bf16 el = (__bf16)(e - (float)eh);
            const int qr = (r & 3) + 8 * (r >> 2) + 4 * half;
            Pb[(w * 2 + 0) * 1152 + qr * 36 + l31] = eh;
            Pb[(w * 2 + 1) * 1152 + qr * 36 + l31] = el;
        }

        #pragma unroll
        for (int ks = 0; ks < 2; ++ks) {
            bf16x8 ah = ld_lds8(Pb + (w * 2 + 0) * 1152 + l31 * 36 + ks * 16 + half * 8);
            bf16x8 al = ld_lds8(Pb + (w * 2 + 1) * 1152 + l31 * 36 + ks * 16 + half * 8);
            #pragma unroll
            for (int nt = 0; nt < 4; ++nt) {
                bf16x8 bh = ld_lds8(XTb + (nt * 32 + l31) * 36 + ks * 16 + half * 8);
                bf16x8 bl = ld_lds8(XTb + 4608 + (nt * 32 + l31) * 36 + ks * 16 + half * 8);
                accM[nt] = MFMA(ah, bh, accM[nt]);
                accM[nt] = MFMA(ah, bl, accM[nt]);
                accM[nt] = MFMA(al, bh, accM[nt]);
            }
        }
    }

    #pragma unroll
    for (int r = 0; r < 16; ++r) mu128p[r] = half_sum32(mu128p[r], half);
    float rno[16];
    #pragma unroll
    for (int r = 0; r < 16; ++r) {
        float p = 0.f;
        #pragma unroll
        for (int nt = 0; nt < 4; ++nt) p += accM[nt][r] * accM[nt][r];
        if (l31 == 0) p -= 2.f * accM[0][r] * accM[0][r];
        p = half_sum32(p, half);
        float negI = -(p + mu128p[r] * mu128p[r]);
        negI = fmaxf(negI, 1e-7f);
        rno[r] = 1.f / (SCf * sqrtf(negI));
    }
    #pragma unroll
    for (int nt = 0; nt < 4; ++nt)
        #pragma unroll
        for (int r = 0; r < 16; ++r) accM[nt][r] *= rno[r];
    #pragma unroll
    for (int r = 0; r < 16; ++r) mu128p[r] *= rno[r];

    __syncthreads();
    __bf16* MuA = (__bf16*)smem + w * (32 * 148);
    #pragma unroll
    for (int r = 0; r < 16; ++r) {
        const int qr = (r & 3) + 8 * (r >> 2) + 4 * half;
        #pragma unroll
        for (int nt = 0; nt < 4; ++nt)
            MuA[qr * 148 + nt * 32 + l31] = (__bf16)accM[nt][r];
        if (l31 == 0) MuA[qr * 148 + 128] = (__bf16)mu128p[r];
        if (l31 >= 1 && l31 <= 15) MuA[qr * 148 + 128 + l31] = (__bf16)0.f;
    }
    bf16x8 Ah[9];
    #pragma unroll
    for (int ks = 0; ks < 9; ++ks) Ah[ks] = ld_lds8(MuA + l31 * 148 + ks * 16 + half * 8);
    #pragma unroll
    for (int r = 0; r < 16; ++r) {
        const int qr = (r & 3) + 8 * (r >> 2) + 4 * half;
        #pragma unroll
        for (int nt = 0; nt < 4; ++nt) {
            float m = accM[nt][r];
            MuA[qr * 148 + nt * 32 + l31] = (__bf16)(m - (float)(__bf16)m);
        }
        if (l31 == 0) {
            float m = mu128p[r];
            MuA[qr * 148 + 128] = (__bf16)(m - (float)(__bf16)m);
        }
    }
    bf16x8 Al[9];
    #pragma unroll
    for (int ks = 0; ks < 9; ++ks) Al[ks] = ld_lds8(MuA + l31 * 148 + ks * 16 + half * 8);

    f32x16 accU[4] = {};
    #pragma unroll
    for (int ks = 0; ks < 9; ++ks) {
        #pragma unroll
        for (int nt = 0; nt < 4; ++nt) {
            bf16x8 bh = *(const bf16x8*)(Woh + (size_t)(nt * 32 + l31) * 144 + ks * 16 + half * 8);
            bf16x8 bl = *(const bf16x8*)(Wol + (size_t)(nt * 32 + l31) * 144 + ks * 16 + half * 8);
            accU[nt] = MFMA(Ah[ks], bh, accU[nt]);
            accU[nt] = MFMA(Ah[ks], bl, accU[nt]);
            accU[nt] = MFMA(Al[ks], bh, accU[nt]);
        }
    }

    float bov[4];
    #pragma unroll
    for (int nt = 0; nt < 4; ++nt) bov[nt] = bo[nt * 32 + l31];
    #pragma unroll
    for (int r = 0; r < 16; ++r) {
        float p = 0.f;
        #pragma unroll
        for (int nt = 0; nt < 4; ++nt) {
            float uv = accU[nt][r] + bov[nt];
            accU[nt][r] = uv;
            p += uv * uv;
        }
        float nn = half_sum32(p, half);
        float nu = fmaxf(sqrtf(nn), 1e-7f);
        float aa = SCf * nu;
        float cf = tanhf(aa) / aa;
        const int qr = (r & 3) + 8 * (r >> 2) + 4 * half;
        const size_t row = (size_t)(b * N_ + qb + w * 32 + qr);
        #pragma unroll
        for (int nt = 0; nt < 4; ++nt)
            Y[row * D_ + nt * 32 + l31] = accU[nt][r] * cf;
        if (l31 == 0) Y2[row] = nn * cf * cf;
    }
}

// ---------------- diagonal Gram blocks: G[b][c][i][k] = <y_i, y_k>, i,k in chunk c ----------------
__global__ __launch_bounds__(256) void k_gram(const float* __restrict__ Y,
                                              float* __restrict__ G) {
    const int c = blockIdx.x, b = blockIdx.y;
    const int t = threadIdx.x, w = t >> 6, l = t & 63;
    const int l31 = l & 31, half = l >> 5;
    const int rt = w >> 1, ct = w & 1;                 // 32x32 tile of the 64x64 block
    const size_t base = (size_t)(b * N_ + c * 64);
    const float* Ar = Y + (base + rt * 32 + l31) * D_;
    const float* Br = Y + (base + ct * 32 + l31) * D_;
    f32x16 acc = {};
    #pragma unroll
    for (int ks = 0; ks < 8; ++ks) {
        const int c0 = ks * 16 + half * 8;
        float4 a0 = *(const float4*)(Ar + c0);
        float4 a1 = *(const float4*)(Ar + c0 + 4);
        float4 b0 = *(const float4*)(Br + c0);
        float4 b1 = *(const float4*)(Br + c0 + 4);
        float av[8] = {a0.x, a0.y, a0.z, a0.w, a1.x, a1.y, a1.z, a1.w};
        float bv[8] = {b0.x, b0.y, b0.z, b0.w, b1.x, b1.y, b1.z, b1.w};
        bf16x8 ah, al, bh, bl;
        #pragma unroll
        for (int j = 0; j < 8; ++j) {
            __bf16 h = (__bf16)av[j]; ah[j] = h; al[j] = (__bf16)(av[j] - (float)h);
            __bf16 g = (__bf16)bv[j]; bh[j] = g; bl[j] = (__bf16)(bv[j] - (float)g);
        }
        acc = MFMA(ah, bh, acc);
        acc = MFMA(ah, bl, acc);
        acc = MFMA(al, bh, acc);
    }
    float* Gb = G + ((size_t)(b * 16 + c) << 12);
    #pragma unroll
    for (int r = 0; r < 16; ++r) {
        const int row = rt * 32 + (r & 3) + 8 * (r >> 2) + 4 * half;
        Gb[row * 64 + ct * 32 + l31] = acc[r];
    }
}

// ---------------- Mobius fold: Gram-scan, all per-step operands in REGISTERS ----------------
// Rounds 4-7 plateaued at 400-570 cyc/step: per-step global loads serialize (~1.6 MLP).
// Fix: G column in VGPRs (double-buffered GA/GB, chunk-ahead prefetch), py2/mask as
// lane-distributed regs read by compile-time readlane, y via block-issued branchless
// 16-load windows. Rescale every 4th step (exact: power-of-2 scaling commutes with fp rounding).
__global__ __launch_bounds__(64, 1) void k_pool(const float* __restrict__ Y,
                                                const float* __restrict__ Y2,
                                                const float* __restrict__ G,
                                                const int* __restrict__ mask,
                                                const int* __restrict__ mflag,
                                                const float* __restrict__ Wf,
                                                const float* __restrict__ bf_,
                                                float* __restrict__ out) {
    __shared__ float  prt[64][65];
    __shared__ double vb[D_];
    const int b = blockIdx.x, l = threadIdx.x;
    const int is8 = *mflag;

    int cl = 0;
    for (int i = l; i < N_; i += 64) cl += read_mask(mask, is8, b * N_ + i);
    const int cntT = (int)(wave_sum64((float)cl) + 0.5f);

    const float2* __restrict__ Yp = (const float2*)(Y + (size_t)b * N_ * D_) + l;   // lane column
    const float*  __restrict__ Gp = G + ((size_t)b << 16) + l;   // block c, row i: Gp[c*4096 + i*64]
    const float*  __restrict__ Pp = Y2 + b * N_;

    float  GA[64], GB[64];
    float  py2A, py2B;
    int    msA, msB;
    float2 yring[2][16];

    // prefill: chunk 0 operands + first y window
    #pragma unroll
    for (int i = 0; i < 64; ++i) GA[i] = Gp[i * 64];
    py2A = Pp[l];
    msA  = read_mask(mask, is8, b * N_ + l);
    #pragma unroll
    for (int k = 0; k < 16; ++k) yring[0][k] = Yp[(size_t)k * 64];

    float U0 = 0.f, U1 = 0.f, g = 0.f, Dh = 1.f, P = 0.f;

    auto chunk = [&](int c, float (&Gc)[64], float (&Gn)[64],
                     float py2c, float& py2n, int msc, int& msn) {
        // prefetch next chunk's operands (full chunk of slack before use)
        const int cn = (c < 15) ? c + 1 : 15;
        #pragma unroll
        for (int i = 0; i < 64; ++i) Gn[i] = Gp[cn * 4096 + i * 64];
        py2n = Pp[cn * 64 + l];
        msn  = read_mask(mask, is8, b * N_ + cn * 64 + l);

        #pragma unroll
        for (int q = 0; q < 4; ++q) {
            // block-issue y prefetch for the next 16-step window (branchless, clamped)
            #pragma unroll
            for (int k = 0; k < 16; ++k) {
                int gs = c * 64 + (q + 1) * 16 + k;
                if (gs > N_ - 1) gs = N_ - 1;
                yring[(q + 1) & 1][k] = Yp[(size_t)gs * 64];
            }
            #pragma unroll
            for (int k = 0; k < 16; ++k) {
                const int ir = q * 16 + k;                      // compile-time lane index
                const float2 yv  = yring[q & 1][k];
                const float  Gv  = Gc[ir];
                const float  py2 = readlane_f(py2c, ir);
                const bool   m   = (__builtin_amdgcn_readlane(msc, ir) != 0);
                // slack terms (previous-state only)
                const float Dsq   = Dh * Dh;
                const float Bh    = fmaf(-0.1f, P, Dsq);
                const float Donep = Dh * fmaf(0.1f, py2, 1.f);
                const float tP    = (0.01f * py2) * P;
                // critical chain: readlane -> Ahat -> select -> g update
                const float puy  = readlane_f(g, ir);
                const float Ahat = fmaf(0.2f, puy, Donep);
                float dh = fmaf(Dh, fmaf(0.2f, puy, Dh), tP);
                dh = fmaxf(dh, 1e-12f * Dsq);
                const float Draw = m ? dh : Dh;
                const float Am   = m ? Ahat : 1.f;
                const float Bm   = m ? Bh   : 0.f;
                const float Pn   = fmaf(Am, fmaf(Am, P, (2.f * Bm) * puy), (Bm * Bm) * py2);
                if ((k & 3) == 3) {                 // exact 2^-e rescale every 4th step
                    const int e = ilogbf(Draw);
                    const float Aef = ldexpf(Am, -e);
                    const float Bef = ldexpf(Bm, -e);
                    Dh = ldexpf(Draw, -e);
                    P  = ldexpf(Pn, -2 * e);
                    g  = fmaf(Aef, g, Bef * Gv);
                    U0 = fmaf(Aef, U0, Bef * yv.x);
                    U1 = fmaf(Aef, U1, Bef * yv.y);
                } else {
                    Dh = Draw;
                    P  = Pn;
                    g  = fmaf(Am, g, Bm * Gv);
                    U0 = fmaf(Am, U0, Bm * yv.x);
                    U1 = fmaf(Am, U1, Bm * yv.y);
                }
            }
        }
        // boundary: re-seed g_k = <U, y_k> for chunk c+1 tokens
        if (c < 15) {
            const int nb = (c + 1) * 64;
            #pragma unroll
            for (int k0 = 0; k0 < 64; k0 += 16) {
                float2 tmp[16];
                #pragma unroll
                for (int k = 0; k < 16; ++k) tmp[k] = Yp[(size_t)(nb + k0 + k) * 64];
                #pragma unroll
                for (int k = 0; k < 16; ++k)
                    prt[k0 + k][l] = fmaf(U0, tmp[k].x, U1 * tmp[k].y);
            }
            float s0 = 0.f, s1 = 0.f, s2 = 0.f, s3 = 0.f;
            #pragma unroll
            for (int p = 0; p < 64; p += 4) {
                s0 += prt[l][p];     s1 += prt[l][p + 1];
                s2 += prt[l][p + 2]; s3 += prt[l][p + 3];
            }
            g = (s0 + s1) + (s2 + s3);
        }
    };

    for (int cc = 0; cc < 8; ++cc) {
        chunk(2 * cc,     GA, GB, py2A, py2B, msA, msB);
        chunk(2 * cc + 1, GB, GA, py2B, py2A, msB, msA);
    }

    // de-homogenize + epilogue (f64)
    const double SCd = 0.31622776601683794;
    const double sD = 1.0 / (double)Dh;
    double a0 = sD * (double)U0, a1 = sD * (double)U1;
    double n2 = fmax((double)P * (sD * sD), 0.0);
    double n = sqrt(n2);
    double tt = SCd * n;
    tt = fmin(fmax(tt, 1e-7), 1.0 - 1e-6);
    int cm = cntT > 0 ? cntT : 1;
    float rf = (float)(1.0 / (double)cm);        // ref casts r to float32
    double r = (double)rf;
    double dv = fmax(SCd * n, 1e-7);
    double f = tanh(r * atanh(tt)) / dv;
    double p0 = a0 * f, p1 = a1 * f;
    double q2;
    if (cntT == 0) {                             // fallback: first token's y
        float2 y0v = *(const float2*)(Y + (size_t)(b * N_) * D_ + 2 * l);
        p0 = y0v.x; p1 = y0v.y;
        q2 = (double)Y2[b * N_];
    } else {
        q2 = f * f * n2;
    }
    double npn = fmax(sqrt(q2), 1e-7);
    double t2 = fmin(fmax(SCd * npn, 1e-7), 1.0 - 1e-6);
    double f2 = atanh(t2) / (SCd * npn);
    vb[2 * l]     = p0 * f2;
    vb[2 * l + 1] = p1 * f2;
    __syncthreads();

    if (l < NC_) {
        double o = (double)bf_[l];
        for (int d = 0; d < D_; ++d) o += vb[d] * (double)Wf[l * D_ + d];
        out[b * NC_ + l] = (float)o;
    }
}

extern "C" void kernel_launch(void* const* d_in, const int* in_sizes, int n_in,
                              void* d_out, int out_size, void* d_ws, size_t ws_size,
                              hipStream_t stream) {
    const int*   tok  = (const int*)d_in[0];
    const int*   mask = (const int*)d_in[1];
    const float* emb  = (const float*)d_in[2];
    const float* Wo   = (const float*)d_in[3];
    const float* bo   = (const float*)d_in[4];
    const float* Wf   = (const float*)d_in[5];
    const float* bf_  = (const float*)d_in[6];
    float* out = (float*)d_out;

    char* wsb = (char*)d_ws;
    __bf16* Xh   = (__bf16*)wsb;                              // 16,777,216 B (reused as Gram after k_attn)
    __bf16* Xl   = (__bf16*)(wsb + 16777216);                 // 16,777,216 B
    float*  X0g  = (float*)(wsb + 33554432);                  //    262,144 B
    float*  X128g= (float*)(wsb + 33816576);                  //    262,144 B
    __bf16* Woh  = (__bf16*)(wsb + 34078720);                 //     36,864 B
    __bf16* Wol  = (__bf16*)(wsb + 34115584);                 //     36,864 B
    float*  Y    = (float*)(wsb + 34152448);                  // 33,554,432 B
    float*  Y2   = (float*)(wsb + 67706880);                  //    262,144 B
    int*    flag = (int*)(wsb + 67969024);                    // total ~67.97 MB
    float*  Gram = (float*)wsb;                               // aliases Xh (dead after k_attn): 16.77 MB

    k_detect_mask<<<dim3(1), dim3(256), 0, stream>>>(mask, flag);
    k_prep_wo<<<dim3(72), dim3(256), 0, stream>>>(Wo, Woh, Wol);
    k_prep<<<dim3(B_ * N_ / 64), dim3(256), 0, stream>>>(tok, emb, Xh, Xl, X0g, X128g);
    k_attn<<<dim3(N_ / QB, B_), dim3(256), 53760, stream>>>(Xh, Xl, X0g, X128g, mask, flag,
                                                            Woh, Wol, bo, Y, Y2);
    k_gram<<<dim3(16, B_), dim3(256), 0, stream>>>(Y, Gram);
    k_pool<<<dim3(B_), dim3(64), 0, stream>>>(Y, Y2, Gram, mask, flag, Wf, bf_, out);
}

// Round 9
// 396.746 us; speedup vs baseline: 1.8537x; 1.0152x over previous
//
#include <hip/hip_runtime.h>
#include <math.h>

#define B_    64
#define N_    1024
#define D_    128
#define DP1   129
#define NC_   10
#define QB    128     // queries per block (4 waves x 32)
#define KT    32      // key tile
#define SCf   0.31622776601683794f
#define SCALE 0.08804509063256238f   // 1/sqrt(129)

typedef __bf16 bf16x8 __attribute__((ext_vector_type(8)));
typedef float  f32x16 __attribute__((ext_vector_type(16)));
typedef unsigned long long ull;

#define MFMA(a, b, c) __builtin_amdgcn_mfma_f32_32x32x16_bf16((a), (b), (c), 0, 0, 0)

static __device__ __forceinline__ float dpp_add_step(float f, int ctrl, int rmask) {
    if (ctrl == 0x111) { int t = __builtin_amdgcn_update_dpp(0, __builtin_bit_cast(int, f), 0x111, 0xf, 0xf, true); return f + __builtin_bit_cast(float, t); }
    if (ctrl == 0x112) { int t = __builtin_amdgcn_update_dpp(0, __builtin_bit_cast(int, f), 0x112, 0xf, 0xf, true); return f + __builtin_bit_cast(float, t); }
    if (ctrl == 0x114) { int t = __builtin_amdgcn_update_dpp(0, __builtin_bit_cast(int, f), 0x114, 0xf, 0xf, true); return f + __builtin_bit_cast(float, t); }
    if (ctrl == 0x118) { int t = __builtin_amdgcn_update_dpp(0, __builtin_bit_cast(int, f), 0x118, 0xf, 0xf, true); return f + __builtin_bit_cast(float, t); }
    if (ctrl == 0x142 && rmask == 0xa) { int t = __builtin_amdgcn_update_dpp(0, __builtin_bit_cast(int, f), 0x142, 0xa, 0xf, true); return f + __builtin_bit_cast(float, t); }
    { int t = __builtin_amdgcn_update_dpp(0, __builtin_bit_cast(int, f), 0x143, 0xc, 0xf, true); return f + __builtin_bit_cast(float, t); }
}

// full 64-lane sum, result broadcast to all lanes
static __device__ __forceinline__ float wave_sum64(float f) {
    f = dpp_add_step(f, 0x111, 0xf);
    f = dpp_add_step(f, 0x112, 0xf);
    f = dpp_add_step(f, 0x114, 0xf);
    f = dpp_add_step(f, 0x118, 0xf);
    f = dpp_add_step(f, 0x142, 0xa);
    f = dpp_add_step(f, 0x143, 0xc);
    return __builtin_bit_cast(float, __builtin_amdgcn_readlane(__builtin_bit_cast(int, f), 63));
}

// per-32-lane-half sum, each lane gets its half's total
static __device__ __forceinline__ float half_sum32(float f, int half) {
    f = dpp_add_step(f, 0x111, 0xf);
    f = dpp_add_step(f, 0x112, 0xf);
    f = dpp_add_step(f, 0x114, 0xf);
    f = dpp_add_step(f, 0x118, 0xf);
    f = dpp_add_step(f, 0x142, 0xa);
    float s0 = __builtin_bit_cast(float, __builtin_amdgcn_readlane(__builtin_bit_cast(int, f), 31));
    float s1 = __builtin_bit_cast(float, __builtin_amdgcn_readlane(__builtin_bit_cast(int, f), 63));
    return half ? s1 : s0;
}

static __device__ __forceinline__ float readlane_f(float v, int lane) {
    return __builtin_bit_cast(float, __builtin_amdgcn_readlane(__builtin_bit_cast(int, v), lane));
}

static __device__ __forceinline__ bf16x8 ld_lds8(const __bf16* p) {
    union { bf16x8 v; ull q[2]; } u;
    u.q[0] = *(const ull*)(p);
    u.q[1] = *(const ull*)(p + 4);
    return u.v;
}

// ---------------- mask dtype detection (int32 vs packed int8 bool) ----------------
__global__ __launch_bounds__(256) void k_detect_mask(const int* __restrict__ mask_w,
                                                     int* __restrict__ flag) {
    __shared__ int bad;
    if (threadIdx.x == 0) bad = 0;
    __syncthreads();
    int local = 0;
    for (int i = threadIdx.x; i < 16384; i += 256) {
        int v = mask_w[i];
        if (v != 0 && v != 1) local = 1;
    }
    if (local) atomicOr(&bad, 1);
    __syncthreads();
    if (threadIdx.x == 0) *flag = bad;   // 1 => data is packed int8 bools
}

static __device__ __forceinline__ int read_mask(const int* mw, int is_i8, int idx) {
    if (is_i8) return (int)((const unsigned char*)mw)[idx];
    return mw[idx];
}

// ---------------- Wo -> bf16 hi/lo, layout [o][144] (K padded 129->144 with zeros) ----------------
__global__ __launch_bounds__(256) void k_prep_wo(const float* __restrict__ Wo,
                                                 __bf16* __restrict__ Woh,
                                                 __bf16* __restrict__ Wol) {
    int idx = blockIdx.x * 256 + threadIdx.x;
    if (idx >= 128 * 144) return;
    int o = idx / 144, d = idx - o * 144;
    float v = (d < DP1) ? Wo[o * DP1 + d] : 0.f;
    __bf16 h = (__bf16)v;
    Woh[idx] = h;
    Wol[idx] = (__bf16)(v - (float)h);
}

// ---------------- embedding + Lorentz expmap0 -> bf16 hi/lo rows + comp0/comp128 f32 ----------------
__global__ __launch_bounds__(256) void k_prep(const int* __restrict__ tok,
                                              const float* __restrict__ emb,
                                              __bf16* __restrict__ Xh, __bf16* __restrict__ Xl,
                                              float* __restrict__ X0g, float* __restrict__ X128g) {
    __shared__ float Xf[64][132];
    const int t = threadIdx.x, w = t >> 6, l = t & 63;
    const int base = blockIdx.x * 64;
    for (int it = 0; it < 16; ++it) {
        const int tk = w * 16 + it;
        const int id = tok[base + tk];
        const float2 v = ((const float2*)(emb + (size_t)id * D_))[l];
        float s = wave_sum64(v.x * v.x + v.y * v.y);
        float nv = fmaxf(sqrtf(s), 1e-7f);
        float a = SCf * nv;
        float a2 = a * a;
        float shc, ch;
        if (a < 0.5f) {
            shc = 1.f + a2 * (1.f/6.f) * (1.f + a2 * (1.f/20.f) * (1.f + a2 * (1.f/42.f)));
            ch  = 1.f + a2 * 0.5f * (1.f + a2 * (1.f/12.f) * (1.f + a2 * (1.f/30.f)));
        } else {
            float ea = __expf(a), ei = 1.f / ea;
            ch = 0.5f * (ea + ei);
            shc = 0.5f * (ea - ei) / a;
        }
        Xf[tk][1 + 2 * l] = v.x * shc;
        Xf[tk][2 + 2 * l] = v.y * shc;
        if (l == 0) Xf[tk][0] = ch / SCf;
    }
    __syncthreads();
    const int tk2 = t >> 2, dg = (t & 3) * 32;
    for (int i = 0; i < 32; i += 8) {
        bf16x8 hv, lv;
        #pragma unroll
        for (int j = 0; j < 8; ++j) {
            float f = Xf[tk2][dg + i + j];
            __bf16 h = (__bf16)f;
            hv[j] = h;
            lv[j] = (__bf16)(f - (float)h);
        }
        *(bf16x8*)(Xh + (size_t)(base + tk2) * D_ + dg + i) = hv;
        *(bf16x8*)(Xl + (size_t)(base + tk2) * D_ + dg + i) = lv;
    }
    if (t < 64) {
        X0g[base + t]   = Xf[t][0];
        X128g[base + t] = Xf[t][D_];
    }
}

// ---------------- fused MFMA attention (r9: no-transpose staging, double-buffered, 1 barrier/tile) ----------------
// Phase B B-fragments are COLUMNS of key-major Krow, read as 8x ds_read_u16 (lane=comp ->
// consecutive addresses -> 2-way bank aliasing, free). Replaces r8's 8192 b16 scatter
// writes/block/tile (SQ_LDS_BANK_CONFLICT 1.26e7) with 512 u16 reads/block/tile.
__global__ __launch_bounds__(256, 2) void k_attn(
        const __bf16* __restrict__ Xh, const __bf16* __restrict__ Xl,
        const float* __restrict__ X0g, const float* __restrict__ X128g,
        const int* __restrict__ mask, const int* __restrict__ mflag,
        const __bf16* __restrict__ Woh, const __bf16* __restrict__ Wol,
        const float* __restrict__ bo,
        float* __restrict__ Y, float* __restrict__ Y2) {
    extern __shared__ char smem[];
    // KBUF[2]: hi 32x132 + lo 32x132 bf16 per buffer (8448 elems, 16896 B); two buffers 33792 B
    __bf16* KB = (__bf16*)smem;
    __bf16* Pb = (__bf16*)(smem + 33792);       // 18432 B (per-wave P hi/lo, rows 36-stride)
    __shared__ float K0s[2][KT];
    __shared__ float K128s[2][KT];
    __shared__ int   Ms[2][KT];

    const int b    = blockIdx.y;
    const int qb   = blockIdx.x * QB;
    const int t    = threadIdx.x;
    const int w    = t >> 6;
    const int l    = t & 63;
    const int l31  = l & 31;
    const int half = l >> 5;
    const int is8  = *mflag;

    // ---- Q fragments (A operand): A[m=lane&31][k=half*8+j], hi/lo, 8 k-steps over comps 0..127 ----
    const size_t qrow = (size_t)(b * N_ + qb + w * 32 + l31);
    bf16x8 qfh[8], qfl[8];
    #pragma unroll
    for (int ks = 0; ks < 8; ++ks) {
        qfh[ks] = *(const bf16x8*)(Xh + qrow * D_ + ks * 16 + half * 8);
        qfl[ks] = *(const bf16x8*)(Xl + qrow * D_ + ks * 16 + half * 8);
    }
    float q0[16], q128[16];
    #pragma unroll
    for (int r = 0; r < 16; ++r) {
        const int qr = (r & 3) + 8 * (r >> 2) + 4 * half;
        q0[r]   = X0g[b * N_ + qb + w * 32 + qr];
        q128[r] = X128g[b * N_ + qb + w * 32 + qr];
    }

    // ---- staging lambdas: global -> regs -> LDS (stride 132, b64 writes: 8B-aligned) ----
    const int skey = t >> 3, sck = t & 7;       // 32 keys x 8 chunks of 16 comps
    bf16x8 svh0, svh1, svl0, svl1;
    float  sK0 = 0.f, sK128 = 0.f;
    int    sM = 0;
    auto ldg_tile = [&](int kt) {
        const size_t kr = (size_t)(b * N_ + kt * KT + skey);
        svh0 = *(const bf16x8*)(Xh + kr * D_ + sck * 16);
        svh1 = *(const bf16x8*)(Xh + kr * D_ + sck * 16 + 8);
        svl0 = *(const bf16x8*)(Xl + kr * D_ + sck * 16);
        svl1 = *(const bf16x8*)(Xl + kr * D_ + sck * 16 + 8);
        if (t < KT) {
            sK0   = X0g[b * N_ + kt * KT + t];
            sK128 = X128g[b * N_ + kt * KT + t];
            sM    = read_mask(mask, is8, b * N_ + kt * KT + t);
        }
    };
    auto st_tile = [&](int buf) {
        __bf16* KH = KB + buf * 8448;
        __bf16* KL = KH + 4224;
        union { bf16x8 v; ull q[2]; } u;
        u.v = svh0; *(ull*)(KH + skey * 132 + sck * 16)      = u.q[0]; *(ull*)(KH + skey * 132 + sck * 16 + 4)  = u.q[1];
        u.v = svh1; *(ull*)(KH + skey * 132 + sck * 16 + 8)  = u.q[0]; *(ull*)(KH + skey * 132 + sck * 16 + 12) = u.q[1];
        u.v = svl0; *(ull*)(KL + skey * 132 + sck * 16)      = u.q[0]; *(ull*)(KL + skey * 132 + sck * 16 + 4)  = u.q[1];
        u.v = svl1; *(ull*)(KL + skey * 132 + sck * 16 + 8)  = u.q[0]; *(ull*)(KL + skey * 132 + sck * 16 + 12) = u.q[1];
        if (t < KT) { K0s[buf][t] = sK0; K128s[buf][t] = sK128; Ms[buf][t] = sM; }
    };

    f32x16 accM[4] = {};
    float  mu128p[16] = {};

    ldg_tile(0);
    st_tile(0);

    for (int kt = 0; kt < N_ / KT; ++kt) {
        __syncthreads();                         // buffer kt&1 fully staged by all threads
        const int cur = kt & 1;
        const int ktn = (kt < 31) ? kt + 1 : 31;
        ldg_tile(ktn);                           // global loads overlap this tile's compute

        const __bf16* KH = KB + cur * 8448;
        const __bf16* KL = KH + 4224;

        // ---- phase A: S = Q . K ----
        f32x16 accS = {};
        #pragma unroll
        for (int ks = 0; ks < 8; ++ks) {
            bf16x8 bh = ld_lds8(KH + l31 * 132 + ks * 16 + half * 8);
            bf16x8 bl = ld_lds8(KL + l31 * 132 + ks * 16 + half * 8);
            accS = MFMA(qfh[ks], bh, accS);
            accS = MFMA(qfh[ks], bl, accS);
            accS = MFMA(qfl[ks], bh, accS);
        }
        const float k0v = K0s[cur][l31], k128v = K128s[cur][l31];
        const int   mv  = Ms[cur][l31];
        #pragma unroll
        for (int r = 0; r < 16; ++r) {
            float sc = (2.f * q0[r] * k0v - accS[r] - q128[r] * k128v) * SCALE;
            float e  = mv ? __expf(sc) : 0.f;
            mu128p[r] += e * k128v;
            __bf16 eh = (__bf16)e;
            __bf16 el = (__bf16)(e - (float)eh);
            const int qr = (r & 3) + 8 * (r >> 2) + 4 * half;
            Pb[(w * 2 + 0) * 1152 + qr * 36 + l31] = eh;
            Pb[(w * 2 + 1) * 1152 + qr * 36 + l31] = el;
        }

        // ---- phase B: mu += P . X; B-fragments = columns of KH/KL (8x u16 each, lane=comp) ----
        #pragma unroll
        for (int ks = 0; ks < 2; ++ks) {
            bf16x8 ah = ld_lds8(Pb + (w * 2 + 0) * 1152 + l31 * 36 + ks * 16 + half * 8);
            bf16x8 al = ld_lds8(Pb + (w * 2 + 1) * 1152 + l31 * 36 + ks * 16 + half * 8);
            #pragma unroll
            for (int nt = 0; nt < 4; ++nt) {
                const int cmp = nt * 32 + l31;
                bf16x8 bh, bl;
                #pragma unroll
                for (int j = 0; j < 8; ++j) {
                    const int key = ks * 16 + half * 8 + j;
                    bh[j] = KH[key * 132 + cmp];
                    bl[j] = KL[key * 132 + cmp];
                }
                accM[nt] = MFMA(ah, bh, accM[nt]);
                accM[nt] = MFMA(ah, bl, accM[nt]);
                accM[nt] = MFMA(al, bh, accM[nt]);
            }
        }

        st_tile(cur ^ 1);                        // write next buffer (nobody reads it this tile)
    }

    #pragma unroll
    for (int r = 0; r < 16; ++r) mu128p[r] = half_sum32(mu128p[r], half);
    float rno[16];
    #pragma unroll
    for (int r = 0; r < 16; ++r) {
        float p = 0.f;
        #pragma unroll
        for (int nt = 0; nt < 4; ++nt) p += accM[nt][r] * accM[nt][r];
        if (l31 == 0) p -= 2.f * accM[0][r] * accM[0][r];
        p = half_sum32(p, half);
        float negI = -(p + mu128p[r] * mu128p[r]);
        negI = fmaxf(negI, 1e-7f);
        rno[r] = 1.f / (SCf * sqrtf(negI));
    }
    #pragma unroll
    for (int nt = 0; nt < 4; ++nt)
        #pragma unroll
        for (int r = 0; r < 16; ++r) accM[nt][r] *= rno[r];
    #pragma unroll
    for (int r = 0; r < 16; ++r) mu128p[r] *= rno[r];

    __syncthreads();                             // done with KB/Pb; alias as MuA
    __bf16* MuA = (__bf16*)smem + w * (32 * 148);
    #pragma unroll
    for (int r = 0; r < 16; ++r) {
        const int qr = (r & 3) + 8 * (r >> 2) + 4 * half;
        #pragma unroll
        for (int nt = 0; nt < 4; ++nt)
            MuA[qr * 148 + nt * 32 + l31] = (__bf16)accM[nt][r];
        if (l31 == 0) MuA[qr * 148 + 128] = (__bf16)mu128p[r];
        if (l31 >= 1 && l31 <= 15) MuA[qr * 148 + 128 + l31] = (__bf16)0.f;
    }
    bf16x8 Ah[9];
    #pragma unroll
    for (int ks = 0; ks < 9; ++ks) Ah[ks] = ld_lds8(MuA + l31 * 148 + ks * 16 + half * 8);
    #pragma unroll
    for (int r = 0; r < 16; ++r) {
        const int qr = (r & 3) + 8 * (r >> 2) + 4 * half;
        #pragma unroll
        for (int nt = 0; nt < 4; ++nt) {
            float m = accM[nt][r];
            MuA[qr * 148 + nt * 32 + l31] = (__bf16)(m - (float)(__bf16)m);
        }
        if (l31 == 0) {
            float m = mu128p[r];
            MuA[qr * 148 + 128] = (__bf16)(m - (float)(__bf16)m);
        }
    }
    bf16x8 Al[9];
    #pragma unroll
    for (int ks = 0; ks < 9; ++ks) Al[ks] = ld_lds8(MuA + l31 * 148 + ks * 16 + half * 8);

    f32x16 accU[4] = {};
    #pragma unroll
    for (int ks = 0; ks < 9; ++ks) {
        #pragma unroll
        for (int nt = 0; nt < 4; ++nt) {
            bf16x8 bh = *(const bf16x8*)(Woh + (size_t)(nt * 32 + l31) * 144 + ks * 16 + half * 8);
            bf16x8 bl = *(const bf16x8*)(Wol + (size_t)(nt * 32 + l31) * 144 + ks * 16 + half * 8);
            accU[nt] = MFMA(Ah[ks], bh, accU[nt]);
            accU[nt] = MFMA(Ah[ks], bl, accU[nt]);
            accU[nt] = MFMA(Al[ks], bh, accU[nt]);
        }
    }

    float bov[4];
    #pragma unroll
    for (int nt = 0; nt < 4; ++nt) bov[nt] = bo[nt * 32 + l31];
    #pragma unroll
    for (int r = 0; r < 16; ++r) {
        float p = 0.f;
        #pragma unroll
        for (int nt = 0; nt < 4; ++nt) {
            float uv = accU[nt][r] + bov[nt];
            accU[nt][r] = uv;
            p += uv * uv;
        }
        float nn = half_sum32(p, half);
        float nu = fmaxf(sqrtf(nn), 1e-7f);
        float aa = SCf * nu;
        float cf = tanhf(aa) / aa;
        const int qr = (r & 3) + 8 * (r >> 2) + 4 * half;
        const size_t row = (size_t)(b * N_ + qb + w * 32 + qr);
        #pragma unroll
        for (int nt = 0; nt < 4; ++nt)
            Y[row * D_ + nt * 32 + l31] = accU[nt][r] * cf;
        if (l31 == 0) Y2[row] = nn * cf * cf;
    }
}

// ---------------- diagonal Gram blocks: G[b][c][i][k] = <y_i, y_k>, i,k in chunk c ----------------
__global__ __launch_bounds__(256) void k_gram(const float* __restrict__ Y,
                                              float* __restrict__ G) {
    const int c = blockIdx.x, b = blockIdx.y;
    const int t = threadIdx.x, w = t >> 6, l = t & 63;
    const int l31 = l & 31, half = l >> 5;
    const int rt = w >> 1, ct = w & 1;                 // 32x32 tile of the 64x64 block
    const size_t base = (size_t)(b * N_ + c * 64);
    const float* Ar = Y + (base + rt * 32 + l31) * D_;
    const float* Br = Y + (base + ct * 32 + l31) * D_;
    f32x16 acc = {};
    #pragma unroll
    for (int ks = 0; ks < 8; ++ks) {
        const int c0 = ks * 16 + half * 8;
        float4 a0 = *(const float4*)(Ar + c0);
        float4 a1 = *(const float4*)(Ar + c0 + 4);
        float4 b0 = *(const float4*)(Br + c0);
        float4 b1 = *(const float4*)(Br + c0 + 4);
        float av[8] = {a0.x, a0.y, a0.z, a0.w, a1.x, a1.y, a1.z, a1.w};
        float bv[8] = {b0.x, b0.y, b0.z, b0.w, b1.x, b1.y, b1.z, b1.w};
        bf16x8 ah, al, bh, bl;
        #pragma unroll
        for (int j = 0; j < 8; ++j) {
            __bf16 h = (__bf16)av[j]; ah[j] = h; al[j] = (__bf16)(av[j] - (float)h);
            __bf16 g = (__bf16)bv[j]; bh[j] = g; bl[j] = (__bf16)(bv[j] - (float)g);
        }
        acc = MFMA(ah, bh, acc);
        acc = MFMA(ah, bl, acc);
        acc = MFMA(al, bh, acc);
    }
    float* Gb = G + ((size_t)(b * 16 + c) << 12);
    #pragma unroll
    for (int r = 0; r < 16; ++r) {
        const int row = rt * 32 + (r & 3) + 8 * (r >> 2) + 4 * half;
        Gb[row * 64 + ct * 32 + l31] = acc[r];
    }
}

// ---------------- Mobius fold: Gram-scan, all per-step operands in REGISTERS ----------------
__global__ __launch_bounds__(64, 1) void k_pool(const float* __restrict__ Y,
                                                const float* __restrict__ Y2,
                                                const float* __restrict__ G,
                                                const int* __restrict__ mask,
                                                const int* __restrict__ mflag,
                                                const float* __restrict__ Wf,
                                                const float* __restrict__ bf_,
                                                float* __restrict__ out) {
    __shared__ float  prt[64][65];
    __shared__ double vb[D_];
    const int b = blockIdx.x, l = threadIdx.x;
    const int is8 = *mflag;

    int cl = 0;
    for (int i = l; i < N_; i += 64) cl += read_mask(mask, is8, b * N_ + i);
    const int cntT = (int)(wave_sum64((float)cl) + 0.5f);

    const float2* __restrict__ Yp = (const float2*)(Y + (size_t)b * N_ * D_) + l;   // lane column
    const float*  __restrict__ Gp = G + ((size_t)b << 16) + l;   // block c, row i: Gp[c*4096 + i*64]
    const float*  __restrict__ Pp = Y2 + b * N_;

    float  GA[64], GB[64];
    float  py2A, py2B;
    int    msA, msB;
    float2 yring[2][16];

    #pragma unroll
    for (int i = 0; i < 64; ++i) GA[i] = Gp[i * 64];
    py2A = Pp[l];
    msA  = read_mask(mask, is8, b * N_ + l);
    #pragma unroll
    for (int k = 0; k < 16; ++k) yring[0][k] = Yp[(size_t)k * 64];

    float U0 = 0.f, U1 = 0.f, g = 0.f, Dh = 1.f, P = 0.f;

    auto chunk = [&](int c, float (&Gc)[64], float (&Gn)[64],
                     float py2c, float& py2n, int msc, int& msn) {
        const int cn = (c < 15) ? c + 1 : 15;
        #pragma unroll
        for (int i = 0; i < 64; ++i) Gn[i] = Gp[cn * 4096 + i * 64];
        py2n = Pp[cn * 64 + l];
        msn  = read_mask(mask, is8, b * N_ + cn * 64 + l);

        #pragma unroll
        for (int q = 0; q < 4; ++q) {
            #pragma unroll
            for (int k = 0; k < 16; ++k) {
                int gs = c * 64 + (q + 1) * 16 + k;
                if (gs > N_ - 1) gs = N_ - 1;
                yring[(q + 1) & 1][k] = Yp[(size_t)gs * 64];
            }
            #pragma unroll
            for (int k = 0; k < 16; ++k) {
                const int ir = q * 16 + k;                      // compile-time lane index
                const float2 yv  = yring[q & 1][k];
                const float  Gv  = Gc[ir];
                const float  py2 = readlane_f(py2c, ir);
                const bool   m   = (__builtin_amdgcn_readlane(msc, ir) != 0);
                const float Dsq   = Dh * Dh;
                const float Bh    = fmaf(-0.1f, P, Dsq);
                const float Donep = Dh * fmaf(0.1f, py2, 1.f);
                const float tP    = (0.01f * py2) * P;
                const float puy  = readlane_f(g, ir);
                const float Ahat = fmaf(0.2f, puy, Donep);
                float dh = fmaf(Dh, fmaf(0.2f, puy, Dh), tP);
                dh = fmaxf(dh, 1e-12f * Dsq);
                const float Draw = m ? dh : Dh;
                const float Am   = m ? Ahat : 1.f;
                const float Bm   = m ? Bh   : 0.f;
                const float Pn   = fmaf(Am, fmaf(Am, P, (2.f * Bm) * puy), (Bm * Bm) * py2);
                if ((k & 3) == 3) {                 // exact 2^-e rescale every 4th step
                    const int e = ilogbf(Draw);
                    const float Aef = ldexpf(Am, -e);
                    const float Bef = ldexpf(Bm, -e);
                    Dh = ldexpf(Draw, -e);
                    P  = ldexpf(Pn, -2 * e);
                    g  = fmaf(Aef, g, Bef * Gv);
                    U0 = fmaf(Aef, U0, Bef * yv.x);
                    U1 = fmaf(Aef, U1, Bef * yv.y);
                } else {
                    Dh = Draw;
                    P  = Pn;
                    g  = fmaf(Am, g, Bm * Gv);
                    U0 = fmaf(Am, U0, Bm * yv.x);
                    U1 = fmaf(Am, U1, Bm * yv.y);
                }
            }
        }
        if (c < 15) {
            const int nb = (c + 1) * 64;
            #pragma unroll
            for (int k0 = 0; k0 < 64; k0 += 16) {
                float2 tmp[16];
                #pragma unroll
                for (int k = 0; k < 16; ++k) tmp[k] = Yp[(size_t)(nb + k0 + k) * 64];
                #pragma unroll
                for (int k = 0; k < 16; ++k)
                    prt[k0 + k][l] = fmaf(U0, tmp[k].x, U1 * tmp[k].y);
            }
            float s0 = 0.f, s1 = 0.f, s2 = 0.f, s3 = 0.f;
            #pragma unroll
            for (int p = 0; p < 64; p += 4) {
                s0 += prt[l][p];     s1 += prt[l][p + 1];
                s2 += prt[l][p + 2]; s3 += prt[l][p + 3];
            }
            g = (s0 + s1) + (s2 + s3);
        }
    };

    for (int cc = 0; cc < 8; ++cc) {
        chunk(2 * cc,     GA, GB, py2A, py2B, msA, msB);
        chunk(2 * cc + 1, GB, GA, py2B, py2A, msB, msA);
    }

    const double SCd = 0.31622776601683794;
    const double sD = 1.0 / (double)Dh;
    double a0 = sD * (double)U0, a1 = sD * (double)U1;
    double n2 = fmax((double)P * (sD * sD), 0.0);
    double n = sqrt(n2);
    double tt = SCd * n;
    tt = fmin(fmax(tt, 1e-7), 1.0 - 1e-6);
    int cm = cntT > 0 ? cntT : 1;
    float rf = (float)(1.0 / (double)cm);        // ref casts r to float32
    double r = (double)rf;
    double dv = fmax(SCd * n, 1e-7);
    double f = tanh(r * atanh(tt)) / dv;
    double p0 = a0 * f, p1 = a1 * f;
    double q2;
    if (cntT == 0) {                             // fallback: first token's y
        float2 y0v = *(const float2*)(Y + (size_t)(b * N_) * D_ + 2 * l);
        p0 = y0v.x; p1 = y0v.y;
        q2 = (double)Y2[b * N_];
    } else {
        q2 = f * f * n2;
    }
    double npn = fmax(sqrt(q2), 1e-7);
    double t2 = fmin(fmax(SCd * npn, 1e-7), 1.0 - 1e-6);
    double f2 = atanh(t2) / (SCd * npn);
    vb[2 * l]     = p0 * f2;
    vb[2 * l + 1] = p1 * f2;
    __syncthreads();

    if (l < NC_) {
        double o = (double)bf_[l];
        for (int d = 0; d < D_; ++d) o += vb[d] * (double)Wf[l * D_ + d];
        out[b * NC_ + l] = (float)o;
    }
}

extern "C" void kernel_launch(void* const* d_in, const int* in_sizes, int n_in,
                              void* d_out, int out_size, void* d_ws, size_t ws_size,
                              hipStream_t stream) {
    const int*   tok  = (const int*)d_in[0];
    const int*   mask = (const int*)d_in[1];
    const float* emb  = (const float*)d_in[2];
    const float* Wo   = (const float*)d_in[3];
    const float* bo   = (const float*)d_in[4];
    const float* Wf   = (const float*)d_in[5];
    const float* bf_  = (const float*)d_in[6];
    float* out = (float*)d_out;

    char* wsb = (char*)d_ws;
    __bf16* Xh   = (__bf16*)wsb;                              // 16,777,216 B (reused as Gram after k_attn)
    __bf16* Xl   = (__bf16*)(wsb + 16777216);                 // 16,777,216 B
    float*  X0g  = (float*)(wsb + 33554432);                  //    262,144 B
    float*  X128g= (float*)(wsb + 33816576);                  //    262,144 B
    __bf16* Woh  = (__bf16*)(wsb + 34078720);                 //     36,864 B
    __bf16* Wol  = (__bf16*)(wsb + 34115584);                 //     36,864 B
    float*  Y    = (float*)(wsb + 34152448);                  // 33,554,432 B
    float*  Y2   = (float*)(wsb + 67706880);                  //    262,144 B
    int*    flag = (int*)(wsb + 67969024);                    // total ~67.97 MB
    float*  Gram = (float*)wsb;                               // aliases Xh (dead after k_attn): 16.77 MB

    k_detect_mask<<<dim3(1), dim3(256), 0, stream>>>(mask, flag);
    k_prep_wo<<<dim3(72), dim3(256), 0, stream>>>(Wo, Woh, Wol);
    k_prep<<<dim3(B_ * N_ / 64), dim3(256), 0, stream>>>(tok, emb, Xh, Xl, X0g, X128g);
    k_attn<<<dim3(N_ / QB, B_), dim3(256), 53760, stream>>>(Xh, Xl, X0g, X128g, mask, flag,
                                                            Woh, Wol, bo, Y, Y2);
    k_gram<<<dim3(16, B_), dim3(256), 0, stream>>>(Y, Gram);
    k_pool<<<dim3(B_), dim3(64), 0, stream>>>(Y, Y2, Gram, mask, flag, Wf, bf_, out);
}

// Round 10
// 394.629 us; speedup vs baseline: 1.8637x; 1.0054x over previous
//
#include <hip/hip_runtime.h>
#include <math.h>

#define B_    64
#define N_    1024
#define D_    128
#define DP1   129
#define NC_   10
#define QB    128     // queries per block (4 waves x 32)
#define KT    32      // key tile
#define SCf   0.31622776601683794f
#define SCALE 0.08804509063256238f   // 1/sqrt(129)

typedef __bf16 bf16x8 __attribute__((ext_vector_type(8)));
typedef float  f32x16 __attribute__((ext_vector_type(16)));
typedef unsigned long long ull;

#define MFMA(a, b, c) __builtin_amdgcn_mfma_f32_32x32x16_bf16((a), (b), (c), 0, 0, 0)

static __device__ __forceinline__ float dpp_add_step(float f, int ctrl, int rmask) {
    if (ctrl == 0x111) { int t = __builtin_amdgcn_update_dpp(0, __builtin_bit_cast(int, f), 0x111, 0xf, 0xf, true); return f + __builtin_bit_cast(float, t); }
    if (ctrl == 0x112) { int t = __builtin_amdgcn_update_dpp(0, __builtin_bit_cast(int, f), 0x112, 0xf, 0xf, true); return f + __builtin_bit_cast(float, t); }
    if (ctrl == 0x114) { int t = __builtin_amdgcn_update_dpp(0, __builtin_bit_cast(int, f), 0x114, 0xf, 0xf, true); return f + __builtin_bit_cast(float, t); }
    if (ctrl == 0x118) { int t = __builtin_amdgcn_update_dpp(0, __builtin_bit_cast(int, f), 0x118, 0xf, 0xf, true); return f + __builtin_bit_cast(float, t); }
    if (ctrl == 0x142 && rmask == 0xa) { int t = __builtin_amdgcn_update_dpp(0, __builtin_bit_cast(int, f), 0x142, 0xa, 0xf, true); return f + __builtin_bit_cast(float, t); }
    { int t = __builtin_amdgcn_update_dpp(0, __builtin_bit_cast(int, f), 0x143, 0xc, 0xf, true); return f + __builtin_bit_cast(float, t); }
}

// full 64-lane sum, result broadcast to all lanes
static __device__ __forceinline__ float wave_sum64(float f) {
    f = dpp_add_step(f, 0x111, 0xf);
    f = dpp_add_step(f, 0x112, 0xf);
    f = dpp_add_step(f, 0x114, 0xf);
    f = dpp_add_step(f, 0x118, 0xf);
    f = dpp_add_step(f, 0x142, 0xa);
    f = dpp_add_step(f, 0x143, 0xc);
    return __builtin_bit_cast(float, __builtin_amdgcn_readlane(__builtin_bit_cast(int, f), 63));
}

// per-32-lane-half sum, each lane gets its half's total
static __device__ __forceinline__ float half_sum32(float f, int half) {
    f = dpp_add_step(f, 0x111, 0xf);
    f = dpp_add_step(f, 0x112, 0xf);
    f = dpp_add_step(f, 0x114, 0xf);
    f = dpp_add_step(f, 0x118, 0xf);
    f = dpp_add_step(f, 0x142, 0xa);
    float s0 = __builtin_bit_cast(float, __builtin_amdgcn_readlane(__builtin_bit_cast(int, f), 31));
    float s1 = __builtin_bit_cast(float, __builtin_amdgcn_readlane(__builtin_bit_cast(int, f), 63));
    return half ? s1 : s0;
}

static __device__ __forceinline__ float readlane_f(float v, int lane) {
    return __builtin_bit_cast(float, __builtin_amdgcn_readlane(__builtin_bit_cast(int, v), lane));
}

static __device__ __forceinline__ bf16x8 ld_lds8(const __bf16* p) {
    union { bf16x8 v; ull q[2]; } u;
    u.q[0] = *(const ull*)(p);
    u.q[1] = *(const ull*)(p + 4);
    return u.v;
}

// ---------------- mask dtype detection (int32 vs packed int8 bool) ----------------
__global__ __launch_bounds__(256) void k_detect_mask(const int* __restrict__ mask_w,
                                                     int* __restrict__ flag) {
    __shared__ int bad;
    if (threadIdx.x == 0) bad = 0;
    __syncthreads();
    int local = 0;
    for (int i = threadIdx.x; i < 16384; i += 256) {
        int v = mask_w[i];
        if (v != 0 && v != 1) local = 1;
    }
    if (local) atomicOr(&bad, 1);
    __syncthreads();
    if (threadIdx.x == 0) *flag = bad;   // 1 => data is packed int8 bools
}

static __device__ __forceinline__ int read_mask(const int* mw, int is_i8, int idx) {
    if (is_i8) return (int)((const unsigned char*)mw)[idx];
    return mw[idx];
}

// ---------------- Wo -> bf16 hi/lo, layout [o][144] (K padded 129->144 with zeros) ----------------
__global__ __launch_bounds__(256) void k_prep_wo(const float* __restrict__ Wo,
                                                 __bf16* __restrict__ Woh,
                                                 __bf16* __restrict__ Wol) {
    int idx = blockIdx.x * 256 + threadIdx.x;
    if (idx >= 128 * 144) return;
    int o = idx / 144, d = idx - o * 144;
    float v = (d < DP1) ? Wo[o * DP1 + d] : 0.f;
    __bf16 h = (__bf16)v;
    Woh[idx] = h;
    Wol[idx] = (__bf16)(v - (float)h);
}

// ---------------- embedding + Lorentz expmap0 -> bf16 hi/lo rows + comp0/comp128 f32 ----------------
__global__ __launch_bounds__(256) void k_prep(const int* __restrict__ tok,
                                              const float* __restrict__ emb,
                                              __bf16* __restrict__ Xh, __bf16* __restrict__ Xl,
                                              float* __restrict__ X0g, float* __restrict__ X128g) {
    __shared__ float Xf[64][132];
    const int t = threadIdx.x, w = t >> 6, l = t & 63;
    const int base = blockIdx.x * 64;
    for (int it = 0; it < 16; ++it) {
        const int tk = w * 16 + it;
        const int id = tok[base + tk];
        const float2 v = ((const float2*)(emb + (size_t)id * D_))[l];
        float s = wave_sum64(v.x * v.x + v.y * v.y);
        float nv = fmaxf(sqrtf(s), 1e-7f);
        float a = SCf * nv;
        float a2 = a * a;
        float shc, ch;
        if (a < 0.5f) {
            shc = 1.f + a2 * (1.f/6.f) * (1.f + a2 * (1.f/20.f) * (1.f + a2 * (1.f/42.f)));
            ch  = 1.f + a2 * 0.5f * (1.f + a2 * (1.f/12.f) * (1.f + a2 * (1.f/30.f)));
        } else {
            float ea = __expf(a), ei = 1.f / ea;
            ch = 0.5f * (ea + ei);
            shc = 0.5f * (ea - ei) / a;
        }
        Xf[tk][1 + 2 * l] = v.x * shc;
        Xf[tk][2 + 2 * l] = v.y * shc;
        if (l == 0) Xf[tk][0] = ch / SCf;
    }
    __syncthreads();
    const int tk2 = t >> 2, dg = (t & 3) * 32;
    for (int i = 0; i < 32; i += 8) {
        bf16x8 hv, lv;
        #pragma unroll
        for (int j = 0; j < 8; ++j) {
            float f = Xf[tk2][dg + i + j];
            __bf16 h = (__bf16)f;
            hv[j] = h;
            lv[j] = (__bf16)(f - (float)h);
        }
        *(bf16x8*)(Xh + (size_t)(base + tk2) * D_ + dg + i) = hv;
        *(bf16x8*)(Xl + (size_t)(base + tk2) * D_ + dg + i) = lv;
    }
    if (t < 64) {
        X0g[base + t]   = Xf[t][0];
        X128g[base + t] = Xf[t][D_];
    }
}

// ---------------- fused MFMA attention (r10: XCD-local batch mapping) ----------------
// r8/r9 invariant at ~174 us with FETCH=154 MB (ideal ~35): grid (x=qchunk,y=batch) put
// XCD = linear%8 = qchunk -> every XCD touched all 64 batches (32 MB working set vs 4 MB L2)
// -> L2 thrash, HBM-bound at 1.17 TB/s. Fix: x=batch -> XCD = batch%8, per-XCD working set
// = 8 batches x 512 KB = 4 MB = L2. K fetched from HBM once, re-read from L2.
__global__ __launch_bounds__(256, 2) void k_attn(
        const __bf16* __restrict__ Xh, const __bf16* __restrict__ Xl,
        const float* __restrict__ X0g, const float* __restrict__ X128g,
        const int* __restrict__ mask, const int* __restrict__ mflag,
        const __bf16* __restrict__ Woh, const __bf16* __restrict__ Wol,
        const float* __restrict__ bo,
        float* __restrict__ Y, float* __restrict__ Y2) {
    extern __shared__ char smem[];
    // KBUF[2]: hi 32x132 + lo 32x132 bf16 per buffer (8448 elems, 16896 B); two buffers 33792 B
    __bf16* KB = (__bf16*)smem;
    __bf16* Pb = (__bf16*)(smem + 33792);       // 18432 B (per-wave P hi/lo, rows 36-stride)
    __shared__ float K0s[2][KT];
    __shared__ float K128s[2][KT];
    __shared__ int   Ms[2][KT];

    const int b    = blockIdx.x;                // batch on x: XCD-local L2 reuse
    const int qb   = blockIdx.y * QB;
    const int t    = threadIdx.x;
    const int w    = t >> 6;
    const int l    = t & 63;
    const int l31  = l & 31;
    const int half = l >> 5;
    const int is8  = *mflag;

    // ---- Q fragments (A operand): A[m=lane&31][k=half*8+j], hi/lo, 8 k-steps over comps 0..127 ----
    const size_t qrow = (size_t)(b * N_ + qb + w * 32 + l31);
    bf16x8 qfh[8], qfl[8];
    #pragma unroll
    for (int ks = 0; ks < 8; ++ks) {
        qfh[ks] = *(const bf16x8*)(Xh + qrow * D_ + ks * 16 + half * 8);
        qfl[ks] = *(const bf16x8*)(Xl + qrow * D_ + ks * 16 + half * 8);
    }
    float q0[16], q128[16];
    #pragma unroll
    for (int r = 0; r < 16; ++r) {
        const int qr = (r & 3) + 8 * (r >> 2) + 4 * half;
        q0[r]   = X0g[b * N_ + qb + w * 32 + qr];
        q128[r] = X128g[b * N_ + qb + w * 32 + qr];
    }

    // ---- staging lambdas: global -> regs -> LDS (stride 132, b64 writes: 8B-aligned) ----
    const int skey = t >> 3, sck = t & 7;       // 32 keys x 8 chunks of 16 comps
    bf16x8 svh0, svh1, svl0, svl1;
    float  sK0 = 0.f, sK128 = 0.f;
    int    sM = 0;
    auto ldg_tile = [&](int kt) {
        const size_t kr = (size_t)(b * N_ + kt * KT + skey);
        svh0 = *(const bf16x8*)(Xh + kr * D_ + sck * 16);
        svh1 = *(const bf16x8*)(Xh + kr * D_ + sck * 16 + 8);
        svl0 = *(const bf16x8*)(Xl + kr * D_ + sck * 16);
        svl1 = *(const bf16x8*)(Xl + kr * D_ + sck * 16 + 8);
        if (t < KT) {
            sK0   = X0g[b * N_ + kt * KT + t];
            sK128 = X128g[b * N_ + kt * KT + t];
            sM    = read_mask(mask, is8, b * N_ + kt * KT + t);
        }
    };
    auto st_tile = [&](int buf) {
        __bf16* KH = KB + buf * 8448;
        __bf16* KL = KH + 4224;
        union { bf16x8 v; ull q[2]; } u;
        u.v = svh0; *(ull*)(KH + skey * 132 + sck * 16)      = u.q[0]; *(ull*)(KH + skey * 132 + sck * 16 + 4)  = u.q[1];
        u.v = svh1; *(ull*)(KH + skey * 132 + sck * 16 + 8)  = u.q[0]; *(ull*)(KH + skey * 132 + sck * 16 + 12) = u.q[1];
        u.v = svl0; *(ull*)(KL + skey * 132 + sck * 16)      = u.q[0]; *(ull*)(KL + skey * 132 + sck * 16 + 4)  = u.q[1];
        u.v = svl1; *(ull*)(KL + skey * 132 + sck * 16 + 8)  = u.q[0]; *(ull*)(KL + skey * 132 + sck * 16 + 12) = u.q[1];
        if (t < KT) { K0s[buf][t] = sK0; K128s[buf][t] = sK128; Ms[buf][t] = sM; }
    };

    f32x16 accM[4] = {};
    float  mu128p[16] = {};

    ldg_tile(0);
    st_tile(0);

    for (int kt = 0; kt < N_ / KT; ++kt) {
        __syncthreads();                         // buffer kt&1 fully staged by all threads
        const int cur = kt & 1;
        const int ktn = (kt < 31) ? kt + 1 : 31;
        ldg_tile(ktn);                           // global loads overlap this tile's compute

        const __bf16* KH = KB + cur * 8448;
        const __bf16* KL = KH + 4224;

        // ---- phase A: S = Q . K ----
        f32x16 accS = {};
        #pragma unroll
        for (int ks = 0; ks < 8; ++ks) {
            bf16x8 bh = ld_lds8(KH + l31 * 132 + ks * 16 + half * 8);
            bf16x8 bl = ld_lds8(KL + l31 * 132 + ks * 16 + half * 8);
            accS = MFMA(qfh[ks], bh, accS);
            accS = MFMA(qfh[ks], bl, accS);
            accS = MFMA(qfl[ks], bh, accS);
        }
        const float k0v = K0s[cur][l31], k128v = K128s[cur][l31];
        const int   mv  = Ms[cur][l31];
        #pragma unroll
        for (int r = 0; r < 16; ++r) {
            float sc = (2.f * q0[r] * k0v - accS[r] - q128[r] * k128v) * SCALE;
            float e  = mv ? __expf(sc) : 0.f;
            mu128p[r] += e * k128v;
            __bf16 eh = (__bf16)e;
            __bf16 el = (__bf16)(e - (float)eh);
            const int qr = (r & 3) + 8 * (r >> 2) + 4 * half;
            Pb[(w * 2 + 0) * 1152 + qr * 36 + l31] = eh;
            Pb[(w * 2 + 1) * 1152 + qr * 36 + l31] = el;
        }

        // ---- phase B: mu += P . X; B-fragments = columns of KH/KL (8x u16 each, lane=comp) ----
        #pragma unroll
        for (int ks = 0; ks < 2; ++ks) {
            bf16x8 ah = ld_lds8(Pb + (w * 2 + 0) * 1152 + l31 * 36 + ks * 16 + half * 8);
            bf16x8 al = ld_lds8(Pb + (w * 2 + 1) * 1152 + l31 * 36 + ks * 16 + half * 8);
            #pragma unroll
            for (int nt = 0; nt < 4; ++nt) {
                const int cmp = nt * 32 + l31;
                bf16x8 bh, bl;
                #pragma unroll
                for (int j = 0; j < 8; ++j) {
                    const int key = ks * 16 + half * 8 + j;
                    bh[j] = KH[key * 132 + cmp];
                    bl[j] = KL[key * 132 + cmp];
                }
                accM[nt] = MFMA(ah, bh, accM[nt]);
                accM[nt] = MFMA(ah, bl, accM[nt]);
                accM[nt] = MFMA(al, bh, accM[nt]);
            }
        }

        st_tile(cur ^ 1);                        // write next buffer (nobody reads it this tile)
    }

    #pragma unroll
    for (int r = 0; r < 16; ++r) mu128p[r] = half_sum32(mu128p[r], half);
    float rno[16];
    #pragma unroll
    for (int r = 0; r < 16; ++r) {
        float p = 0.f;
        #pragma unroll
        for (int nt = 0; nt < 4; ++nt) p += accM[nt][r] * accM[nt][r];
        if (l31 == 0) p -= 2.f * accM[0][r] * accM[0][r];
        p = half_sum32(p, half);
        float negI = -(p + mu128p[r] * mu128p[r]);
        negI = fmaxf(negI, 1e-7f);
        rno[r] = 1.f / (SCf * sqrtf(negI));
    }
    #pragma unroll
    for (int nt = 0; nt < 4; ++nt)
        #pragma unroll
        for (int r = 0; r < 16; ++r) accM[nt][r] *= rno[r];
    #pragma unroll
    for (int r = 0; r < 16; ++r) mu128p[r] *= rno[r];

    __syncthreads();                             // done with KB/Pb; alias as MuA
    __bf16* MuA = (__bf16*)smem + w * (32 * 148);
    #pragma unroll
    for (int r = 0; r < 16; ++r) {
        const int qr = (r & 3) + 8 * (r >> 2) + 4 * half;
        #pragma unroll
        for (int nt = 0; nt < 4; ++nt)
            MuA[qr * 148 + nt * 32 + l31] = (__bf16)accM[nt][r];
        if (l31 == 0) MuA[qr * 148 + 128] = (__bf16)mu128p[r];
        if (l31 >= 1 && l31 <= 15) MuA[qr * 148 + 128 + l31] = (__bf16)0.f;
    }
    bf16x8 Ah[9];
    #pragma unroll
    for (int ks = 0; ks < 9; ++ks) Ah[ks] = ld_lds8(MuA + l31 * 148 + ks * 16 + half * 8);
    #pragma unroll
    for (int r = 0; r < 16; ++r) {
        const int qr = (r & 3) + 8 * (r >> 2) + 4 * half;
        #pragma unroll
        for (int nt = 0; nt < 4; ++nt) {
            float m = accM[nt][r];
            MuA[qr * 148 + nt * 32 + l31] = (__bf16)(m - (float)(__bf16)m);
        }
        if (l31 == 0) {
            float m = mu128p[r];
            MuA[qr * 148 + 128] = (__bf16)(m - (float)(__bf16)m);
        }
    }
    bf16x8 Al[9];
    #pragma unroll
    for (int ks = 0; ks < 9; ++ks) Al[ks] = ld_lds8(MuA + l31 * 148 + ks * 16 + half * 8);

    f32x16 accU[4] = {};
    #pragma unroll
    for (int ks = 0; ks < 9; ++ks) {
        #pragma unroll
        for (int nt = 0; nt < 4; ++nt) {
            bf16x8 bh = *(const bf16x8*)(Woh + (size_t)(nt * 32 + l31) * 144 + ks * 16 + half * 8);
            bf16x8 bl = *(const bf16x8*)(Wol + (size_t)(nt * 32 + l31) * 144 + ks * 16 + half * 8);
            accU[nt] = MFMA(Ah[ks], bh, accU[nt]);
            accU[nt] = MFMA(Ah[ks], bl, accU[nt]);
            accU[nt] = MFMA(Al[ks], bh, accU[nt]);
        }
    }

    float bov[4];
    #pragma unroll
    for (int nt = 0; nt < 4; ++nt) bov[nt] = bo[nt * 32 + l31];
    #pragma unroll
    for (int r = 0; r < 16; ++r) {
        float p = 0.f;
        #pragma unroll
        for (int nt = 0; nt < 4; ++nt) {
            float uv = accU[nt][r] + bov[nt];
            accU[nt][r] = uv;
            p += uv * uv;
        }
        float nn = half_sum32(p, half);
        float nu = fmaxf(sqrtf(nn), 1e-7f);
        float aa = SCf * nu;
        float cf = tanhf(aa) / aa;
        const int qr = (r & 3) + 8 * (r >> 2) + 4 * half;
        const size_t row = (size_t)(b * N_ + qb + w * 32 + qr);
        #pragma unroll
        for (int nt = 0; nt < 4; ++nt)
            Y[row * D_ + nt * 32 + l31] = accU[nt][r] * cf;
        if (l31 == 0) Y2[row] = nn * cf * cf;
    }
}

// ---------------- diagonal Gram blocks: G[b][c][i][k] = <y_i, y_k>, i,k in chunk c ----------------
__global__ __launch_bounds__(256) void k_gram(const float* __restrict__ Y,
                                              float* __restrict__ G) {
    const int c = blockIdx.x, b = blockIdx.y;
    const int t = threadIdx.x, w = t >> 6, l = t & 63;
    const int l31 = l & 31, half = l >> 5;
    const int rt = w >> 1, ct = w & 1;                 // 32x32 tile of the 64x64 block
    const size_t base = (size_t)(b * N_ + c * 64);
    const float* Ar = Y + (base + rt * 32 + l31) * D_;
    const float* Br = Y + (base + ct * 32 + l31) * D_;
    f32x16 acc = {};
    #pragma unroll
    for (int ks = 0; ks < 8; ++ks) {
        const int c0 = ks * 16 + half * 8;
        float4 a0 = *(const float4*)(Ar + c0);
        float4 a1 = *(const float4*)(Ar + c0 + 4);
        float4 b0 = *(const float4*)(Br + c0);
        float4 b1 = *(const float4*)(Br + c0 + 4);
        float av[8] = {a0.x, a0.y, a0.z, a0.w, a1.x, a1.y, a1.z, a1.w};
        float bv[8] = {b0.x, b0.y, b0.z, b0.w, b1.x, b1.y, b1.z, b1.w};
        bf16x8 ah, al, bh, bl;
        #pragma unroll
        for (int j = 0; j < 8; ++j) {
            __bf16 h = (__bf16)av[j]; ah[j] = h; al[j] = (__bf16)(av[j] - (float)h);
            __bf16 g = (__bf16)bv[j]; bh[j] = g; bl[j] = (__bf16)(bv[j] - (float)g);
        }
        acc = MFMA(ah, bh, acc);
        acc = MFMA(ah, bl, acc);
        acc = MFMA(al, bh, acc);
    }
    float* Gb = G + ((size_t)(b * 16 + c) << 12);
    #pragma unroll
    for (int r = 0; r < 16; ++r) {
        const int row = rt * 32 + (r & 3) + 8 * (r >> 2) + 4 * half;
        Gb[row * 64 + ct * 32 + l31] = acc[r];
    }
}

// ---------------- Mobius fold: Gram-scan, all per-step operands in REGISTERS ----------------
__global__ __launch_bounds__(64, 1) void k_pool(const float* __restrict__ Y,
                                                const float* __restrict__ Y2,
                                                const float* __restrict__ G,
                                                const int* __restrict__ mask,
                                                const int* __restrict__ mflag,
                                                const float* __restrict__ Wf,
                                                const float* __restrict__ bf_,
                                                float* __restrict__ out) {
    __shared__ float  prt[64][65];
    __shared__ double vb[D_];
    const int b = blockIdx.x, l = threadIdx.x;
    const int is8 = *mflag;

    int cl = 0;
    for (int i = l; i < N_; i += 64) cl += read_mask(mask, is8, b * N_ + i);
    const int cntT = (int)(wave_sum64((float)cl) + 0.5f);

    const float2* __restrict__ Yp = (const float2*)(Y + (size_t)b * N_ * D_) + l;   // lane column
    const float*  __restrict__ Gp = G + ((size_t)b << 16) + l;   // block c, row i: Gp[c*4096 + i*64]
    const float*  __restrict__ Pp = Y2 + b * N_;

    float  GA[64], GB[64];
    float  py2A, py2B;
    int    msA, msB;
    float2 yring[2][16];

    #pragma unroll
    for (int i = 0; i < 64; ++i) GA[i] = Gp[i * 64];
    py2A = Pp[l];
    msA  = read_mask(mask, is8, b * N_ + l);
    #pragma unroll
    for (int k = 0; k < 16; ++k) yring[0][k] = Yp[(size_t)k * 64];

    float U0 = 0.f, U1 = 0.f, g = 0.f, Dh = 1.f, P = 0.f;

    auto chunk = [&](int c, float (&Gc)[64], float (&Gn)[64],
                     float py2c, float& py2n, int msc, int& msn) {
        const int cn = (c < 15) ? c + 1 : 15;
        #pragma unroll
        for (int i = 0; i < 64; ++i) Gn[i] = Gp[cn * 4096 + i * 64];
        py2n = Pp[cn * 64 + l];
        msn  = read_mask(mask, is8, b * N_ + cn * 64 + l);

        #pragma unroll
        for (int q = 0; q < 4; ++q) {
            #pragma unroll
            for (int k = 0; k < 16; ++k) {
                int gs = c * 64 + (q + 1) * 16 + k;
                if (gs > N_ - 1) gs = N_ - 1;
                yring[(q + 1) & 1][k] = Yp[(size_t)gs * 64];
            }
            #pragma unroll
            for (int k = 0; k < 16; ++k) {
                const int ir = q * 16 + k;                      // compile-time lane index
                const float2 yv  = yring[q & 1][k];
                const float  Gv  = Gc[ir];
                const float  py2 = readlane_f(py2c, ir);
                const bool   m   = (__builtin_amdgcn_readlane(msc, ir) != 0);
                const float Dsq   = Dh * Dh;
                const float Bh    = fmaf(-0.1f, P, Dsq);
                const float Donep = Dh * fmaf(0.1f, py2, 1.f);
                const float tP    = (0.01f * py2) * P;
                const float puy  = readlane_f(g, ir);
                const float Ahat = fmaf(0.2f, puy, Donep);
                float dh = fmaf(Dh, fmaf(0.2f, puy, Dh), tP);
                dh = fmaxf(dh, 1e-12f * Dsq);
                const float Draw = m ? dh : Dh;
                const float Am   = m ? Ahat : 1.f;
                const float Bm   = m ? Bh   : 0.f;
                const float Pn   = fmaf(Am, fmaf(Am, P, (2.f * Bm) * puy), (Bm * Bm) * py2);
                if ((k & 3) == 3) {                 // exact 2^-e rescale every 4th step
                    const int e = ilogbf(Draw);
                    const float Aef = ldexpf(Am, -e);
                    const float Bef = ldexpf(Bm, -e);
                    Dh = ldexpf(Draw, -e);
                    P  = ldexpf(Pn, -2 * e);
                    g  = fmaf(Aef, g, Bef * Gv);
                    U0 = fmaf(Aef, U0, Bef * yv.x);
                    U1 = fmaf(Aef, U1, Bef * yv.y);
                } else {
                    Dh = Draw;
                    P  = Pn;
                    g  = fmaf(Am, g, Bm * Gv);
                    U0 = fmaf(Am, U0, Bm * yv.x);
                    U1 = fmaf(Am, U1, Bm * yv.y);
                }
            }
        }
        if (c < 15) {
            const int nb = (c + 1) * 64;
            #pragma unroll
            for (int k0 = 0; k0 < 64; k0 += 16) {
                float2 tmp[16];
                #pragma unroll
                for (int k = 0; k < 16; ++k) tmp[k] = Yp[(size_t)(nb + k0 + k) * 64];
                #pragma unroll
                for (int k = 0; k < 16; ++k)
                    prt[k0 + k][l] = fmaf(U0, tmp[k].x, U1 * tmp[k].y);
            }
            float s0 = 0.f, s1 = 0.f, s2 = 0.f, s3 = 0.f;
            #pragma unroll
            for (int p = 0; p < 64; p += 4) {
                s0 += prt[l][p];     s1 += prt[l][p + 1];
                s2 += prt[l][p + 2]; s3 += prt[l][p + 3];
            }
            g = (s0 + s1) + (s2 + s3);
        }
    };

    for (int cc = 0; cc < 8; ++cc) {
        chunk(2 * cc,     GA, GB, py2A, py2B, msA, msB);
        chunk(2 * cc + 1, GB, GA, py2B, py2A, msB, msA);
    }

    const double SCd = 0.31622776601683794;
    const double sD = 1.0 / (double)Dh;
    double a0 = sD * (double)U0, a1 = sD * (double)U1;
    double n2 = fmax((double)P * (sD * sD), 0.0);
    double n = sqrt(n2);
    double tt = SCd * n;
    tt = fmin(fmax(tt, 1e-7), 1.0 - 1e-6);
    int cm = cntT > 0 ? cntT : 1;
    float rf = (float)(1.0 / (double)cm);        // ref casts r to float32
    double r = (double)rf;
    double dv = fmax(SCd * n, 1e-7);
    double f = tanh(r * atanh(tt)) / dv;
    double p0 = a0 * f, p1 = a1 * f;
    double q2;
    if (cntT == 0) {                             // fallback: first token's y
        float2 y0v = *(const float2*)(Y + (size_t)(b * N_) * D_ + 2 * l);
        p0 = y0v.x; p1 = y0v.y;
        q2 = (double)Y2[b * N_];
    } else {
        q2 = f * f * n2;
    }
    double npn = fmax(sqrt(q2), 1e-7);
    double t2 = fmin(fmax(SCd * npn, 1e-7), 1.0 - 1e-6);
    double f2 = atanh(t2) / (SCd * npn);
    vb[2 * l]     = p0 * f2;
    vb[2 * l + 1] = p1 * f2;
    __syncthreads();

    if (l < NC_) {
        double o = (double)bf_[l];
        for (int d = 0; d < D_; ++d) o += vb[d] * (double)Wf[l * D_ + d];
        out[b * NC_ + l] = (float)o;
    }
}

extern "C" void kernel_launch(void* const* d_in, const int* in_sizes, int n_in,
                              void* d_out, int out_size, void* d_ws, size_t ws_size,
                              hipStream_t stream) {
    const int*   tok  = (const int*)d_in[0];
    const int*   mask = (const int*)d_in[1];
    const float* emb  = (const float*)d_in[2];
    const float* Wo   = (const float*)d_in[3];
    const float* bo   = (const float*)d_in[4];
    const float* Wf   = (const float*)d_in[5];
    const float* bf_  = (const float*)d_in[6];
    float* out = (float*)d_out;

    char* wsb = (char*)d_ws;
    __bf16* Xh   = (__bf16*)wsb;                              // 16,777,216 B (reused as Gram after k_attn)
    __bf16* Xl   = (__bf16*)(wsb + 16777216);                 // 16,777,216 B
    float*  X0g  = (float*)(wsb + 33554432);                  //    262,144 B
    float*  X128g= (float*)(wsb + 33816576);                  //    262,144 B
    __bf16* Woh  = (__bf16*)(wsb + 34078720);                 //     36,864 B
    __bf16* Wol  = (__bf16*)(wsb + 34115584);                 //     36,864 B
    float*  Y    = (float*)(wsb + 34152448);                  // 33,554,432 B
    float*  Y2   = (float*)(wsb + 67706880);                  //    262,144 B
    int*    flag = (int*)(wsb + 67969024);                    // total ~67.97 MB
    float*  Gram = (float*)wsb;                               // aliases Xh (dead after k_attn): 16.77 MB

    k_detect_mask<<<dim3(1), dim3(256), 0, stream>>>(mask, flag);
    k_prep_wo<<<dim3(72), dim3(256), 0, stream>>>(Wo, Woh, Wol);
    k_prep<<<dim3(B_ * N_ / 64), dim3(256), 0, stream>>>(tok, emb, Xh, Xl, X0g, X128g);
    k_attn<<<dim3(B_, N_ / QB), dim3(256), 53760, stream>>>(Xh, Xl, X0g, X128g, mask, flag,
                                                            Woh, Wol, bo, Y, Y2);
    k_gram<<<dim3(16, B_), dim3(256), 0, stream>>>(Y, Gram);
    k_pool<<<dim3(B_), dim3(64), 0, stream>>>(Y, Y2, Gram, mask, flag, Wf, bf_, out);
}